// Round 5
// baseline (286.739 us; speedup 1.0000x reference)
//
#include <hip/hip_runtime.h>

// AVWGCN: B=32, N=2048, C=64, O=64, K=3, D=16
// R18 changes vs R17 (preamble stuck at 42us though its traffic floor is 12us; removing
// z-gen saved only 2us -> tail-bound, not BW-bound. Culprit found by address inspection:
// Wp segment loads base[i*64+o] with i varying per-lane = 64-way-split wave loads,
// 48 serial iters, on 16 CUs dispatched LAST -> ~20us latency tail):
//  - Wp segment rewritten coalesced: o=lane, ki wave-uniform -> 256B coalesced loads,
//    LDS transpose tile tw[64][193] (pad 193 -> conflict-free), contiguous f32x4/u16x4
//    output runs. Runs at bid 0 (dispatched first).
//  - preamble reordered: [0,16) Wp | [16,80) bias | [80,1104) x-T.
//  - adj/saw conversion split into convk (1536 blocks) for per-segment attribution.
// Rest identical to R17 (zsm, counted-vmcnt gemm_bt256, wn-mode gconv).

typedef unsigned short u16;
typedef float f32x4 __attribute__((ext_vector_type(4)));
typedef __bf16 bf16x8 __attribute__((ext_vector_type(8)));
typedef unsigned short u16x8 __attribute__((ext_vector_type(8)));

#define PSTRIDE ((size_t)2048 * 2048)

__device__ __forceinline__ u16 f2bf(float f) {
    unsigned u = __float_as_uint(f);
    u += 0x7FFFu + ((u >> 16) & 1u);   // RNE
    return (u16)(u >> 16);
}
__device__ __forceinline__ float bf2f(u16 h) {
    return __uint_as_float((unsigned)h << 16);
}
__device__ __forceinline__ void gl_lds16(const void* g, void* l) {
    __builtin_amdgcn_global_load_lds(
        (const __attribute__((address_space(1))) unsigned*)g,
        (__attribute__((address_space(3))) unsigned*)l, 16, 0, 0);
}

// ---------------------------------------------------------------- zsm: z-gen + softmax
// 256 blocks x 256 thr. Block b computes rows [8b, 8b+8) of softmax(relu(E@E^T)) -> Acat bf16.
__global__ __launch_bounds__(256)
void zsm(const float* __restrict__ E, u16* __restrict__ Acat) {
    __shared__ float Et[16 * 2048];
    __shared__ float redm[4][8], reds[4][8];
    const int tid = threadIdx.x;
    const int r0 = blockIdx.x * 8;

#pragma unroll
    for (int k = 0; k < 8; ++k) {
        const int n = tid + 256 * k;
        const float4* Er = (const float4*)(E + (size_t)n * 16);
        float4 e0 = Er[0], e1 = Er[1], e2 = Er[2], e3 = Er[3];
        Et[0 * 2048 + n] = e0.x;  Et[1 * 2048 + n] = e0.y;
        Et[2 * 2048 + n] = e0.z;  Et[3 * 2048 + n] = e0.w;
        Et[4 * 2048 + n] = e1.x;  Et[5 * 2048 + n] = e1.y;
        Et[6 * 2048 + n] = e1.z;  Et[7 * 2048 + n] = e1.w;
        Et[8 * 2048 + n] = e2.x;  Et[9 * 2048 + n] = e2.y;
        Et[10 * 2048 + n] = e2.z; Et[11 * 2048 + n] = e2.w;
        Et[12 * 2048 + n] = e3.x; Et[13 * 2048 + n] = e3.y;
        Et[14 * 2048 + n] = e3.z; Et[15 * 2048 + n] = e3.w;
    }
    __syncthreads();

    float z[8][8] = {};
#pragma unroll
    for (int d = 0; d < 16; ++d) {
        const float* row = Et + d * 2048;
        float ev[8];
#pragma unroll
        for (int k = 0; k < 8; ++k) ev[k] = row[tid + 256 * k];
#pragma unroll
        for (int r = 0; r < 8; ++r) {
            float e = row[r0 + r];   // broadcast
#pragma unroll
            for (int k = 0; k < 8; ++k) z[r][k] = fmaf(e, ev[k], z[r][k]);
        }
    }
    float mr[8];
#pragma unroll
    for (int r = 0; r < 8; ++r) {
        float m = 0.f;
#pragma unroll
        for (int k = 0; k < 8; ++k) { z[r][k] = fmaxf(z[r][k], 0.f); m = fmaxf(m, z[r][k]); }
        mr[r] = m;
    }
#pragma unroll
    for (int off = 32; off; off >>= 1)
#pragma unroll
        for (int r = 0; r < 8; ++r) mr[r] = fmaxf(mr[r], __shfl_xor(mr[r], off, 64));
    if ((tid & 63) == 0) {
#pragma unroll
        for (int r = 0; r < 8; ++r) redm[tid >> 6][r] = mr[r];
    }
    __syncthreads();
#pragma unroll
    for (int r = 0; r < 8; ++r)
        mr[r] = fmaxf(fmaxf(redm[0][r], redm[1][r]), fmaxf(redm[2][r], redm[3][r]));
    float sr[8];
#pragma unroll
    for (int r = 0; r < 8; ++r) {
        float s = 0.f;
#pragma unroll
        for (int k = 0; k < 8; ++k) { z[r][k] = __expf(z[r][k] - mr[r]); s += z[r][k]; }
        sr[r] = s;
    }
#pragma unroll
    for (int off = 32; off; off >>= 1)
#pragma unroll
        for (int r = 0; r < 8; ++r) sr[r] += __shfl_xor(sr[r], off, 64);
    if ((tid & 63) == 0) {
#pragma unroll
        for (int r = 0; r < 8; ++r) reds[tid >> 6][r] = sr[r];
    }
    __syncthreads();
#pragma unroll
    for (int r = 0; r < 8; ++r) {
        float inv = 1.f / (reds[0][r] + reds[1][r] + reds[2][r] + reds[3][r]);
        u16* orow = Acat + (size_t)(r0 + r) * 4096;
#pragma unroll
        for (int k = 0; k < 8; ++k) orow[tid + 256 * k] = f2bf(z[r][k] * inv);
    }
}

// ---------------------------------------------------------------- convk: adj+saw -> bf16
// 1536 blocks x 8 batched float4/thread, grid-stride.
__global__ __launch_bounds__(256)
void convk(const float* __restrict__ adj, const float* __restrict__ saw,
           u16* __restrict__ Acat, u16* __restrict__ sawb) {
    const size_t NADJ = 1048576, STRIDE = (size_t)1536 * 256;
    const size_t e0 = (size_t)blockIdx.x * 256 + threadIdx.x;
    float4 v[8];
#pragma unroll
    for (int it = 0; it < 8; ++it) {
        size_t idx = e0 + (size_t)it * STRIDE;
        const float* src = (idx < NADJ) ? (adj + idx * 4) : (saw + (idx - NADJ) * 4);
        v[it] = *(const float4*)src;
    }
#pragma unroll
    for (int it = 0; it < 8; ++it) {
        size_t idx = e0 + (size_t)it * STRIDE;
        ushort4 o = make_ushort4(f2bf(v[it].x), f2bf(v[it].y), f2bf(v[it].z), f2bf(v[it].w));
        if (idx < NADJ) {
            size_t j = idx * 4;
            int n = (int)(j >> 11), c = (int)(j & 2047);
            *(ushort4*)(Acat + (size_t)n * 4096 + 2048 + c) = o;
        } else {
            *(ushort4*)(sawb + (idx - NADJ) * 4) = o;
        }
    }
}

// ---------------------------------------------------------------- preamble
// grid 1104: [0,16) Wp coalesced | [16,80) bias | [80,1104) x-T
__global__ __launch_bounds__(256)
void preamble(const float* __restrict__ E, const float* __restrict__ x,
              const float* __restrict__ Wp, const float* __restrict__ bp,
              u16* __restrict__ xtT, u16* __restrict__ Wpb, float* __restrict__ Wpbf,
              float* __restrict__ bias, u16* __restrict__ xn, int mode) {
    __shared__ float tw[64][193];   // Wp transpose tile (pad 193 -> conflict-free)
    __shared__ u16 t[64][65];       // x-T tile
    const int bid = blockIdx.x, tid = threadIdx.x;

    if (bid < 16) {
        const int d = bid;
        const float* base = Wp + (size_t)d * 12288;    // [k][i][o]
        const int o = tid & 63, seg = tid >> 6;        // seg 0..3, ki = seg*48 + j
#pragma unroll
        for (int j = 0; j < 48; ++j) {
            int ki = seg * 48 + j;
            int k = ki >> 6, i = ki & 63;              // wave-uniform
            float v;
            if (k == 0)      v = base[i * 64 + o] - base[8192 + i * 64 + o];
            else if (k == 1) v = base[4096 + i * 64 + o];
            else             v = 2.f * base[8192 + i * 64 + o];
            tw[o][ki] = v;
        }
        __syncthreads();
#pragma unroll
        for (int it = 0; it < 12; ++it) {
            int idx = tid + it * 256;
            int oo = idx / 48, q = idx - oo * 48;      // q in [0,48)
            float v0 = tw[oo][q * 4], v1 = tw[oo][q * 4 + 1];
            float v2 = tw[oo][q * 4 + 2], v3 = tw[oo][q * 4 + 3];
            size_t dst = (size_t)(d * 64 + oo) * 192 + q * 4;
            *(float4*)(Wpbf + dst) = make_float4(v0, v1, v2, v3);
            *(ushort4*)(Wpb + dst) = make_ushort4(f2bf(v0), f2bf(v1), f2bf(v2), f2bf(v3));
        }
    } else if (bid < 80) {
        const int nb = bid - 16;
#pragma unroll
        for (int it = 0; it < 8; ++it) {
            int idx = tid + it * 256;
            int n = nb * 32 + (idx >> 6), o = idx & 63;
            float s = 0.f;
#pragma unroll
            for (int d = 0; d < 16; ++d) s = fmaf(E[n * 16 + d], bp[d * 64 + o], s);
            bias[(size_t)n * 64 + o] = s;
        }
    } else {
        int local = bid - 80;
        int m0 = (local & 31) * 64, b = local >> 5;
        int c = tid & 63, g = tid >> 6;
#pragma unroll
        for (int r = 0; r < 16; ++r) {
            int mm = g * 16 + r;
            t[mm][c] = f2bf(x[((size_t)b * 2048 + m0 + mm) * 64 + c]);
        }
        __syncthreads();
#pragma unroll
        for (int r = 0; r < 16; ++r) {
            int cc = g * 16 + r;
            xtT[((size_t)b * 64 + cc) * 2048 + m0 + c] = t[c][cc];
        }
        if (mode) {
#pragma unroll
            for (int r = 0; r < 16; ++r) {
                int mm = g * 16 + r;
                xn[((size_t)(m0 + mm)) * 2048 + b * 64 + c] = t[mm][c];
            }
        }
    }
}

// ---------------------------------------------------------------- mid: wgen only (wn mode)
__global__ __launch_bounds__(256)
void mid(const float* __restrict__ E, const float* __restrict__ Wpbf,
         u16* __restrict__ Wnb) {
    __shared__ float Es[32 * 16];
    const int w = blockIdx.x, tid = threadIdx.x;
    const int c0 = (w % 12) * 1024, n0 = (w / 12) * 32;
    for (int j = tid; j < 512; j += 256) Es[j] = E[(size_t)n0 * 16 + j];
    float4 wf[16];
#pragma unroll
    for (int d = 0; d < 16; ++d)
        wf[d] = *(const float4*)(Wpbf + (size_t)d * 12288 + c0 + tid * 4);
    __syncthreads();
    for (int nl = 0; nl < 32; ++nl) {
        float4 s = make_float4(0.f, 0.f, 0.f, 0.f);
#pragma unroll
        for (int d = 0; d < 16; ++d) {
            float e = Es[nl * 16 + d];
            s.x = fmaf(e, wf[d].x, s.x);
            s.y = fmaf(e, wf[d].y, s.y);
            s.z = fmaf(e, wf[d].z, s.z);
            s.w = fmaf(e, wf[d].w, s.w);
        }
        *(ushort4*)(Wnb + (size_t)(n0 + nl) * 12288 + c0 + tid * 4) =
            make_ushort4(f2bf(s.x), f2bf(s.y), f2bf(s.z), f2bf(s.w));
    }
}

// ---------------------------------------------------------------- GEMM 256x256, BK=64, split-K
__global__ __launch_bounds__(512, 2)
void gemm_bt256(const u16* __restrict__ A, const u16* __restrict__ Bt,
                u16* __restrict__ Cp, int M, int N, int K, int Kh) {
    __shared__ alignas(16) u16 As[2][256 * 64];
    __shared__ alignas(16) u16 Bs[2][256 * 64];
    const int tid = threadIdx.x, lane = tid & 63, wave = tid >> 6;

    const int nbx = gridDim.x, nby = gridDim.y, nbz = gridDim.z;
    const int nwg = nbx * nby * nbz;
    int lin = (blockIdx.z * nby + blockIdx.y) * nbx + blockIdx.x;
    if ((nwg & 7) == 0) lin = (lin & 7) * (nwg >> 3) + (lin >> 3);
    const int bz = lin / (nbx * nby);
    const int r2 = lin - bz * nbx * nby;
    const int by = r2 / nbx, bx = r2 - by * nbx;

    const int m0 = by * 256, n0 = bx * 256;
    const int kbeg = bz * Kh;
    const int NT = Kh >> 6;
    const int wm = (wave >> 2) * 128, wn = (wave & 3) * 64;
    const int ml = lane & 15, c0l = lane >> 4;

    int sI[4], rowI[4], gcI[4];
#pragma unroll
    for (int r = 0; r < 4; ++r) {
        int s = r * 512 + tid;
        sI[r] = s; rowI[r] = s >> 3; gcI[r] = (s & 7) ^ ((s >> 3) & 7);
    }

    f32x4 acc[8][4] = {};
    bf16x8 af[4][2], bv[2][2];

#define LOADA(r_, kt_, buf_) \
    gl_lds16(A + (size_t)(m0 + rowI[r_]) * K + (kt_) + gcI[r_] * 8, \
             &As[buf_][sI[r_] * 8])
#define LOADB(r_, kt_, buf_) \
    gl_lds16(Bt + (size_t)(n0 + rowI[r_]) * K + (kt_) + gcI[r_] * 8, \
             &Bs[buf_][sI[r_] * 8])

#define DSRA(qa_) \
    _Pragma("unroll") \
    for (int i = 0; i < 4; ++i) { \
        const int mr = wm + (qa_) * 64 + i * 16 + ml; \
        _Pragma("unroll") \
        for (int ks = 0; ks < 2; ++ks) \
            af[i][ks] = *(const bf16x8*)(Asc + mr * 64 + (((c0l + ks * 4) ^ (mr & 7)) * 8)); \
    }
#define DSRB(qb_) \
    _Pragma("unroll") \
    for (int j = 0; j < 2; ++j) { \
        const int nr = wn + (qb_) * 32 + j * 16 + ml; \
        _Pragma("unroll") \
        for (int ks = 0; ks < 2; ++ks) \
            bv[j][ks] = *(const bf16x8*)(Bsc + nr * 64 + (((c0l + ks * 4) ^ (nr & 7)) * 8)); \
    }
#define MMQ(io_, jo_) \
    __builtin_amdgcn_s_barrier(); \
    asm volatile("s_waitcnt lgkmcnt(0)" ::: "memory"); \
    __builtin_amdgcn_s_setprio(1); \
    _Pragma("unroll") \
    for (int ks = 0; ks < 2; ++ks) \
        _Pragma("unroll") \
        for (int i = 0; i < 4; ++i) \
            _Pragma("unroll") \
            for (int j = 0; j < 2; ++j) \
                acc[(io_) + i][(jo_) + j] = __builtin_amdgcn_mfma_f32_16x16x32_bf16( \
                    af[i][ks], bv[j][ks], acc[(io_) + i][(jo_) + j], 0, 0, 0); \
    __builtin_amdgcn_s_setprio(0);

#pragma unroll
    for (int r = 0; r < 4; ++r) LOADA(r, kbeg, 0);
#pragma unroll
    for (int r = 0; r < 4; ++r) LOADB(r, kbeg, 0);
    asm volatile("s_waitcnt vmcnt(0)" ::: "memory");
    __builtin_amdgcn_s_barrier();

    for (int t = 0; t < NT - 1; ++t) {
        const int cur = t & 1, nxt = cur ^ 1;
        const u16* Asc = As[cur];
        const u16* Bsc = Bs[cur];
        const int k1 = kbeg + (t + 1) * 64;

        DSRA(0); DSRB(0);
        LOADB(0, k1, nxt); LOADB(1, k1, nxt);
        MMQ(0, 0);
        __builtin_amdgcn_s_barrier();

        DSRB(1);
        LOADB(2, k1, nxt); LOADB(3, k1, nxt);
        MMQ(0, 2);
        asm volatile("s_waitcnt vmcnt(4)" ::: "memory");
        __builtin_amdgcn_s_barrier();

        DSRA(1);
        LOADA(0, k1, nxt); LOADA(2, k1, nxt);
        MMQ(4, 2);
        __builtin_amdgcn_s_barrier();

        DSRB(0);
        LOADA(1, k1, nxt); LOADA(3, k1, nxt);
        MMQ(4, 0);
        asm volatile("s_waitcnt vmcnt(2)" ::: "memory");
        __builtin_amdgcn_s_barrier();
    }

    {
        const int cur = (NT - 1) & 1;
        const u16* Asc = As[cur];
        const u16* Bsc = Bs[cur];

        DSRA(0); DSRB(0);
        MMQ(0, 0);
        __builtin_amdgcn_s_barrier();

        DSRB(1);
        MMQ(0, 2);
        asm volatile("s_waitcnt vmcnt(0)" ::: "memory");
        __builtin_amdgcn_s_barrier();

        DSRA(1);
        MMQ(4, 2);
        __builtin_amdgcn_s_barrier();

        DSRB(0);
        MMQ(4, 0);
    }

#undef LOADA
#undef LOADB
#undef DSRA
#undef DSRB
#undef MMQ

    const int col_l = lane & 15, rl = (lane >> 4) * 4;
    u16* Cz = Cp + (size_t)bz * M * N;
#pragma unroll
    for (int i = 0; i < 8; ++i)
#pragma unroll
        for (int j = 0; j < 4; ++j)
#pragma unroll
            for (int r = 0; r < 4; ++r) {
                int row = m0 + wm + i * 16 + rl + r;
                int col = n0 + wn + j * 16 + col_l;
                Cz[(size_t)row * N + col] = f2bf(acc[i][j][r]);
            }
}

// ---------------------------------------------------------------- reduce_z
__global__ __launch_bounds__(256)
void reduce_z(const u16* __restrict__ p, const u16* __restrict__ Acat,
              u16* __restrict__ S) {
    const size_t base = ((size_t)blockIdx.x * 256 + threadIdx.x) * 4;
    const size_t STRIDE = (size_t)1024 * 256 * 4;
#pragma unroll
    for (int it = 0; it < 4; ++it) {
        size_t j = base + (size_t)it * STRIDE;
        ushort4 p0 = *(const ushort4*)(p + j);
        ushort4 p1 = *(const ushort4*)(p + PSTRIDE + j);
        ushort4 p2 = *(const ushort4*)(p + 2 * PSTRIDE + j);
        ushort4 p3 = *(const ushort4*)(p + 3 * PSTRIDE + j);
        int row = (int)(j >> 11), col = (int)(j & 2047);
        ushort4 sp = *(const ushort4*)(Acat + (size_t)row * 4096 + col);
        ushort4 ad = *(const ushort4*)(Acat + (size_t)row * 4096 + 2048 + col);
        float z0 = bf2f(p0.x) + bf2f(p1.x) + bf2f(p2.x) + bf2f(p3.x);
        float z1 = bf2f(p0.y) + bf2f(p1.y) + bf2f(p2.y) + bf2f(p3.y);
        float z2 = bf2f(p0.z) + bf2f(p1.z) + bf2f(p2.z) + bf2f(p3.z);
        float z3 = bf2f(p0.w) + bf2f(p1.w) + bf2f(p2.w) + bf2f(p3.w);
        float s0 = 1.f / (1.f + __expf(-z0)), s1 = 1.f / (1.f + __expf(-z1));
        float s2 = 1.f / (1.f + __expf(-z2)), s3 = 1.f / (1.f + __expf(-z3));
        ushort4 o = make_ushort4(
            f2bf(s0 * bf2f(ad.x) + (1.f - s0) * bf2f(sp.x)),
            f2bf(s1 * bf2f(ad.y) + (1.f - s1) * bf2f(sp.y)),
            f2bf(s2 * bf2f(ad.z) + (1.f - s2) * bf2f(sp.z)),
            f2bf(s3 * bf2f(ad.w) + (1.f - s3) * bf2f(sp.w)));
        *(ushort4*)(S + j) = o;
    }
}

// ---------------------------------------------------------------- reduceT
__global__ __launch_bounds__(256)
void reduceT(const u16* __restrict__ p, u16* __restrict__ xg1o,
             u16* __restrict__ xg1T, int mode) {
    __shared__ u16 t[64][68];
    int bx = blockIdx.x * 64, by = blockIdx.y * 64;
    int cg = threadIdx.x & 15, rg = threadIdx.x >> 4;
    int b = bx >> 6;
#pragma unroll
    for (int rr = 0; rr < 4; ++rr) {
        int row = rg * 4 + rr;
        size_t idx = (size_t)(by + row) * 2048 + bx + cg * 4;
        ushort4 q0 = *(const ushort4*)(p + idx);
        ushort4 q1 = *(const ushort4*)(p + PSTRIDE + idx);
        ushort4 q2 = *(const ushort4*)(p + 2 * PSTRIDE + idx);
        ushort4 q3 = *(const ushort4*)(p + 3 * PSTRIDE + idx);
        ushort4 v = make_ushort4(
            f2bf(bf2f(q0.x) + bf2f(q1.x) + bf2f(q2.x) + bf2f(q3.x)),
            f2bf(bf2f(q0.y) + bf2f(q1.y) + bf2f(q2.y) + bf2f(q3.y)),
            f2bf(bf2f(q0.z) + bf2f(q1.z) + bf2f(q2.z) + bf2f(q3.z)),
            f2bf(bf2f(q0.w) + bf2f(q1.w) + bf2f(q2.w) + bf2f(q3.w)));
        if (mode) *(ushort4*)(xg1o + idx) = v;
        else      *(ushort4*)(xg1o + ((size_t)b * 2048 + by + row) * 64 + cg * 4) = v;
        *(ushort4*)(&t[row][cg * 4]) = v;
    }
    __syncthreads();
    int c = threadIdx.x & 63, g = threadIdx.x >> 6;
#pragma unroll
    for (int r = 0; r < 16; ++r) {
        int row = g * 16 + r;
        xg1T[(size_t)(bx + row) * 2048 + by + c] = t[c][row];
    }
}

// ---------------------------------------------------------------- gconv_wn (Wn mode)
__global__ __launch_bounds__(256, 4)
void gconv_wn(const u16* __restrict__ xn, const u16* __restrict__ xg1n,
              const u16* __restrict__ p, const u16* __restrict__ Wnb,
              const float* __restrict__ bias, float* __restrict__ out) {
    __shared__ alignas(16) u16 As[32 * 192];
    __shared__ alignas(16) u16 Bs[64 * 192];
    const int n = blockIdx.x, tid = threadIdx.x;
    const int lane = tid & 63, wave = tid >> 6;
    const int wn2 = wave * 16;
    const int ml = lane & 15, c0l = lane >> 4;
    const int col = lane & 15, rl = (lane >> 4) * 4;

#pragma unroll
    for (int it = 0; it < 6; ++it) {
        int s = tid + it * 256;
        int row = s / 24, sc = s - row * 24;
        int gc = (sc & 24) | ((sc ^ row) & 7);
        gl_lds16(Wnb + (size_t)n * 12288 + (size_t)row * 192 + gc * 8, Bs + (size_t)s * 8);
    }
#pragma unroll
    for (int it = 0; it < 3; ++it) {
        int s = tid + it * 256;
        int row = s / 24, sc = s - row * 24;
        int gc = (sc & 24) | ((sc ^ row) & 7);
        u16x8 v;
        if (gc < 8) {
            v = *(const u16x8*)(xn + (size_t)n * 2048 + row * 64 + (gc & 7) * 8);
        } else if (gc < 16) {
            v = *(const u16x8*)(xg1n + (size_t)n * 2048 + row * 64 + (gc & 7) * 8);
        } else {
            const u16* pp = p + (size_t)n * 2048 + row * 64 + (gc & 7) * 8;
            u16x8 q0 = *(const u16x8*)pp;
            u16x8 q1 = *(const u16x8*)(pp + PSTRIDE);
            u16x8 q2 = *(const u16x8*)(pp + 2 * PSTRIDE);
            u16x8 q3 = *(const u16x8*)(pp + 3 * PSTRIDE);
#pragma unroll
            for (int tt = 0; tt < 8; ++tt)
                v[tt] = f2bf(bf2f(q0[tt]) + bf2f(q1[tt]) + bf2f(q2[tt]) + bf2f(q3[tt]));
        }
        *(u16x8*)(As + (size_t)s * 8) = v;
    }
    float bv0 = bias[(size_t)n * 64 + wn2 + col];
    f32x4 acc[2];
#pragma unroll
    for (int mt = 0; mt < 2; ++mt)
#pragma unroll
        for (int r = 0; r < 4; ++r) acc[mt][r] = bv0;
    __syncthreads();

#pragma unroll
    for (int ks = 0; ks < 6; ++ks) {
        int c = c0l + ks * 4;
        int o = wn2 + ml;
        bf16x8 bfrag = *(const bf16x8*)(Bs + (o * 24 + ((c & 24) | ((c ^ (o & 7)) & 7))) * 8);
#pragma unroll
        for (int mt = 0; mt < 2; ++mt) {
            int m = mt * 16 + ml;
            bf16x8 afrag = *(const bf16x8*)(As + (m * 24 + ((c & 24) | ((c ^ (m & 7)) & 7))) * 8);
            acc[mt] = __builtin_amdgcn_mfma_f32_16x16x32_bf16(afrag, bfrag, acc[mt], 0, 0, 0);
        }
    }
#pragma unroll
    for (int mt = 0; mt < 2; ++mt)
#pragma unroll
        for (int r = 0; r < 4; ++r) {
            int b = mt * 16 + rl + r;
            out[((size_t)b * 2048 + n) * 64 + wn2 + col] = acc[mt][r];
        }
}

// ---------------------------------------------------------------- gconv_mfma (legacy fallback)
__global__ __launch_bounds__(256, 2)
void gconv_mfma(const float* __restrict__ x, const u16* __restrict__ xg1,
                const u16* __restrict__ p, const u16* __restrict__ Wpb,
                const float* __restrict__ bias, const float* __restrict__ E,
                float* __restrict__ out) {
    __shared__ alignas(16) float El[16 * 128];
    const int tid = threadIdx.x, lane = tid & 63, wave = tid >> 6;
    const int m0 = blockIdx.x * 128, nb = m0 & 2047, bB = m0 >> 11;
    const int wm = (wave >> 1) * 64, wn = (wave & 1) * 32;
    const int ml = lane & 15, c0l = lane >> 4;
    const int col_l = lane & 15, rl = (lane >> 4) * 4;

#pragma unroll
    for (int it = 0; it < 8; ++it) {
        int idx = tid + it * 256;
        El[idx] = E[(size_t)(nb + (idx & 127)) * 16 + (idx >> 7)];
    }
    __syncthreads();

    bf16x8 af[4][6];
#pragma unroll
    for (int i = 0; i < 4; ++i) {
        const int row = m0 + wm + i * 16 + ml;
        const int n = row & 2047;
#pragma unroll
        for (int ks = 0; ks < 2; ++ks) {
            const float* xp = x + (size_t)row * 64 + (c0l + ks * 4) * 8;
            float4 a = *(const float4*)xp, b4 = *(const float4*)(xp + 4);
            u16x8 v;
            v[0] = f2bf(a.x);  v[1] = f2bf(a.y);  v[2] = f2bf(a.z);  v[3] = f2bf(a.w);
            v[4] = f2bf(b4.x); v[5] = f2bf(b4.y); v[6] = f2bf(b4.z); v[7] = f2bf(b4.w);
            af[i][ks] = __builtin_bit_cast(bf16x8, v);
        }
#pragma unroll
        for (int ks = 2; ks < 4; ++ks)
            af[i][ks] = *(const bf16x8*)(xg1 + (size_t)row * 64 + (c0l + ks * 4 - 8) * 8);
#pragma unroll
        for (int ks = 4; ks < 6; ++ks) {
            const u16* pp = p + (size_t)n * 2048 + bB * 64 + (c0l + ks * 4 - 16) * 8;
            u16x8 q0 = *(const u16x8*)pp;
            u16x8 q1 = *(const u16x8*)(pp + PSTRIDE);
            u16x8 q2 = *(const u16x8*)(pp + 2 * PSTRIDE);
            u16x8 q3 = *(const u16x8*)(pp + 3 * PSTRIDE);
            u16x8 v;
#pragma unroll
            for (int tt = 0; tt < 8; ++tt)
                v[tt] = f2bf(bf2f(q0[tt]) + bf2f(q1[tt]) + bf2f(q2[tt]) + bf2f(q3[tt]));
            af[i][ks] = __builtin_bit_cast(bf16x8, v);
        }
    }

    f32x4 oacc[4][2];
#pragma unroll
    for (int i = 0; i < 4; ++i)
#pragma unroll
        for (int j = 0; j < 2; ++j)
#pragma unroll
            for (int r = 0; r < 4; ++r)
                oacc[i][j][r] = bias[(size_t)(nb + wm + i * 16 + rl + r) * 64 + wn + j * 16 + col_l];

#pragma unroll 2
    for (int d = 0; d < 16; ++d) {
        bf16x8 bv[2][6];
#pragma unroll
        for (int j = 0; j < 2; ++j) {
            const u16* wp = Wpb + (size_t)(d * 64 + wn + j * 16 + ml) * 192 + c0l * 8;
#pragma unroll
            for (int ks = 0; ks < 6; ++ks)
                bv[j][ks] = *(const bf16x8*)(wp + ks * 32);
        }
        f32x4 tmp[4][2] = {};
#pragma unroll
        for (int ks = 0; ks < 6; ++ks)
#pragma unroll
            for (int i = 0; i < 4; ++i)
#pragma unroll
                for (int j = 0; j < 2; ++j)
                    tmp[i][j] = __builtin_amdgcn_mfma_f32_16x16x32_bf16(af[i][ks], bv[j][ks], tmp[i][j], 0, 0, 0);
#pragma unroll
        for (int i = 0; i < 4; ++i) {
            f32x4 ev = *(const f32x4*)(El + d * 128 + wm + i * 16 + rl);
#pragma unroll
            for (int r = 0; r < 4; ++r)
#pragma unroll
                for (int j = 0; j < 2; ++j)
                    oacc[i][j][r] = fmaf(ev[r], tmp[i][j][r], oacc[i][j][r]);
        }
    }
#pragma unroll
    for (int i = 0; i < 4; ++i)
#pragma unroll
        for (int j = 0; j < 2; ++j)
#pragma unroll
            for (int r = 0; r < 4; ++r)
                out[(size_t)(m0 + wm + i * 16 + rl + r) * 64 + wn + j * 16 + col_l] = oacc[i][j][r];
}

// ---------------------------------------------------------------- launch
extern "C" void kernel_launch(void* const* d_in, const int* in_sizes, int n_in,
                              void* d_out, int out_size, void* d_ws, size_t ws_size,
                              hipStream_t stream) {
    const float* x   = (const float*)d_in[0];
    const float* E   = (const float*)d_in[1];
    const float* adj = (const float*)d_in[2];
    const float* Wp  = (const float*)d_in[3];
    const float* bp  = (const float*)d_in[4];
    const float* saw = (const float*)d_in[5];
    float* out = (float*)d_out;

    char* ws = (char*)d_ws;
    const size_t MB = 1u << 20;
    const int wn_mode = (ws_size >= 140 * MB) ? 1 : 0;

    u16*   Acat  = (u16*)(ws);                  // [0,16M)
    u16*   sawb  = (u16*)(ws + 16 * MB);        // [16,32M)
    u16*   XtT   = (u16*)(ws + 32 * MB);        // [32,40M)
    u16*   Wpb   = (u16*)(ws + 40 * MB);        // [40,40.4M) bf16
    float* bias  = (float*)(ws + 41 * MB);      // [41,41.5M)
    float* Wpbf  = (float*)(ws + 42 * MB);      // [42,42.8M) fp32
    u16*   part  = (u16*)(ws + 48 * MB);        // [48,80M)
    u16*   S_bf  = (u16*)(ws + 16 * MB);        // [16,24M)
    u16*   xg1T  = (u16*)(ws + 24 * MB);        // [24,32M)
    u16*   xg1o  = (u16*)(ws);                  // [0,8M)
    u16*   xn    = (u16*)(ws + 80 * MB);        // [80,88M)   wn only
    u16*   Wnb   = (u16*)(ws + 88 * MB);        // [88,138.4M) wn only

    zsm<<<256, 256, 0, stream>>>(E, Acat);
    preamble<<<1104, 256, 0, stream>>>(E, x, Wp, bp, XtT, Wpb, Wpbf, bias, xn, wn_mode);
    convk<<<1536, 256, 0, stream>>>(adj, saw, Acat, sawb);
    if (wn_mode)
        mid<<<768, 256, 0, stream>>>(E, Wpbf, Wnb);

    gemm_bt256<<<dim3(8, 8, 4), 512, 0, stream>>>(Acat, sawb, part, 2048, 2048, 4096, 1024);
    reduce_z<<<1024, 256, 0, stream>>>(part, Acat, S_bf);
    gemm_bt256<<<dim3(8, 8, 4), 512, 0, stream>>>(S_bf, XtT, part, 2048, 2048, 2048, 512);
    reduceT<<<dim3(32, 32), 256, 0, stream>>>(part, xg1o, xg1T, wn_mode);
    gemm_bt256<<<dim3(8, 8, 4), 512, 0, stream>>>(S_bf, xg1T, part, 2048, 2048, 2048, 512);

    if (wn_mode)
        gconv_wn<<<2048, 256, 0, stream>>>(xn, xg1o, part, Wnb, bias, out);
    else
        gconv_mfma<<<512, 256, 0, stream>>>(x, xg1o, part, Wpb, bias, E, out);
}

// Round 6
// 278.372 us; speedup vs baseline: 1.0301x; 1.0301x over previous
//
#include <hip/hip_runtime.h>

// AVWGCN: B=32, N=2048, C=64, O=64, K=3, D=16
// R19 changes vs R18 (totals track dispatch COUNT: 8->271us, 9->276us, 10->287us;
// per-kernel wins eaten by ~5-10us per dispatch boundary (launch + tail drain)):
//  - preA: zsm + adj/saw-conv + x-T + Wp(coalesced) + bias fused into ONE 2896-block
//    dispatch. zsm LDS 128->64KB via two-phase Et staging (d 0..7 then 8..15, same
//    accumulation order -> bit-identical); 64KB smem union -> 2 blocks/CU all segments.
//  - rzmid: reduce_z + wgen(mid) fused (1792 blocks) - both ready after gemm1.
//  - Dispatches 10 -> 7. gemm_bt256 et al unchanged.

typedef unsigned short u16;
typedef float f32x4 __attribute__((ext_vector_type(4)));
typedef __bf16 bf16x8 __attribute__((ext_vector_type(8)));
typedef unsigned short u16x8 __attribute__((ext_vector_type(8)));

#define PSTRIDE ((size_t)2048 * 2048)

__device__ __forceinline__ u16 f2bf(float f) {
    unsigned u = __float_as_uint(f);
    u += 0x7FFFu + ((u >> 16) & 1u);   // RNE
    return (u16)(u >> 16);
}
__device__ __forceinline__ float bf2f(u16 h) {
    return __uint_as_float((unsigned)h << 16);
}
__device__ __forceinline__ void gl_lds16(const void* g, void* l) {
    __builtin_amdgcn_global_load_lds(
        (const __attribute__((address_space(1))) unsigned*)g,
        (__attribute__((address_space(3))) unsigned*)l, 16, 0, 0);
}

// ---------------------------------------------------------------- preA (fully fused)
// grid 2896: [0,256) zsm | [256,1792) adj+saw conv | [1792,2816) x-T
//            | [2816,2832) Wp coalesced | [2832,2896) bias
__global__ __launch_bounds__(256)
void preA(const float* __restrict__ E, const float* __restrict__ adj,
          const float* __restrict__ saw, const float* __restrict__ x,
          const float* __restrict__ Wp, const float* __restrict__ bp,
          u16* __restrict__ Acat, u16* __restrict__ sawb, u16* __restrict__ xtT,
          u16* __restrict__ Wpb, float* __restrict__ Wpbf,
          float* __restrict__ bias, u16* __restrict__ xn, int mode) {
    __shared__ __align__(16) char smem[65536];
    const int bid = blockIdx.x, tid = threadIdx.x;

    if (bid < 256) {
        // ---- zsm: softmax(relu(E@E^T)) rows [8b,8b+8) -> Acat bf16, two-phase Et
        float* Et8 = (float*)smem;            // [8][2048] fp32 = 64KB
        const int r0 = bid * 8;
        float z[8][8] = {};
#pragma unroll
        for (int ph = 0; ph < 2; ++ph) {
            if (ph) __syncthreads();          // all reads of phase-0 Et done
#pragma unroll
            for (int k = 0; k < 8; ++k) {
                const int n = tid + 256 * k;
                const float4* Er = (const float4*)(E + (size_t)n * 16) + ph * 2;
                float4 e0 = Er[0], e1 = Er[1];
                Et8[0 * 2048 + n] = e0.x; Et8[1 * 2048 + n] = e0.y;
                Et8[2 * 2048 + n] = e0.z; Et8[3 * 2048 + n] = e0.w;
                Et8[4 * 2048 + n] = e1.x; Et8[5 * 2048 + n] = e1.y;
                Et8[6 * 2048 + n] = e1.z; Et8[7 * 2048 + n] = e1.w;
            }
            __syncthreads();
#pragma unroll
            for (int d = 0; d < 8; ++d) {     // accumulation order = d 0..15 (bit-identical)
                const float* row = Et8 + d * 2048;
                float ev[8];
#pragma unroll
                for (int k = 0; k < 8; ++k) ev[k] = row[tid + 256 * k];
#pragma unroll
                for (int r = 0; r < 8; ++r) {
                    float e = row[r0 + r];    // broadcast
#pragma unroll
                    for (int k = 0; k < 8; ++k) z[r][k] = fmaf(e, ev[k], z[r][k]);
                }
            }
        }
        __syncthreads();                       // Et8 dead; reuse smem for reductions
        float (*redm)[8] = (float(*)[8])smem;
        float (*reds)[8] = (float(*)[8])(smem + 256);

        float mr[8];
#pragma unroll
        for (int r = 0; r < 8; ++r) {
            float m = 0.f;
#pragma unroll
            for (int k = 0; k < 8; ++k) { z[r][k] = fmaxf(z[r][k], 0.f); m = fmaxf(m, z[r][k]); }
            mr[r] = m;
        }
#pragma unroll
        for (int off = 32; off; off >>= 1)
#pragma unroll
            for (int r = 0; r < 8; ++r) mr[r] = fmaxf(mr[r], __shfl_xor(mr[r], off, 64));
        if ((tid & 63) == 0) {
#pragma unroll
            for (int r = 0; r < 8; ++r) redm[tid >> 6][r] = mr[r];
        }
        __syncthreads();
#pragma unroll
        for (int r = 0; r < 8; ++r)
            mr[r] = fmaxf(fmaxf(redm[0][r], redm[1][r]), fmaxf(redm[2][r], redm[3][r]));
        float sr[8];
#pragma unroll
        for (int r = 0; r < 8; ++r) {
            float s = 0.f;
#pragma unroll
            for (int k = 0; k < 8; ++k) { z[r][k] = __expf(z[r][k] - mr[r]); s += z[r][k]; }
            sr[r] = s;
        }
#pragma unroll
        for (int off = 32; off; off >>= 1)
#pragma unroll
            for (int r = 0; r < 8; ++r) sr[r] += __shfl_xor(sr[r], off, 64);
        if ((tid & 63) == 0) {
#pragma unroll
            for (int r = 0; r < 8; ++r) reds[tid >> 6][r] = sr[r];
        }
        __syncthreads();
#pragma unroll
        for (int r = 0; r < 8; ++r) {
            float inv = 1.f / (reds[0][r] + reds[1][r] + reds[2][r] + reds[3][r]);
            u16* orow = Acat + (size_t)(r0 + r) * 4096;
#pragma unroll
            for (int k = 0; k < 8; ++k) orow[tid + 256 * k] = f2bf(z[r][k] * inv);
        }
    } else if (bid < 1792) {
        // ---- adj (1M float4) + saw (2M float4) -> bf16, batched grid-stride
        const size_t NADJ = 1048576, STRIDE = (size_t)1536 * 256;
        const size_t e0 = (size_t)(bid - 256) * 256 + tid;
        float4 v[8];
#pragma unroll
        for (int it = 0; it < 8; ++it) {
            size_t idx = e0 + (size_t)it * STRIDE;
            const float* src = (idx < NADJ) ? (adj + idx * 4) : (saw + (idx - NADJ) * 4);
            v[it] = *(const float4*)src;
        }
#pragma unroll
        for (int it = 0; it < 8; ++it) {
            size_t idx = e0 + (size_t)it * STRIDE;
            ushort4 o = make_ushort4(f2bf(v[it].x), f2bf(v[it].y), f2bf(v[it].z), f2bf(v[it].w));
            if (idx < NADJ) {
                size_t j = idx * 4;
                int n = (int)(j >> 11), c = (int)(j & 2047);
                *(ushort4*)(Acat + (size_t)n * 4096 + 2048 + c) = o;
            } else {
                *(ushort4*)(sawb + (idx - NADJ) * 4) = o;
            }
        }
    } else if (bid < 2816) {
        // ---- x transpose (+xn in wn mode)
        u16 (*t)[65] = (u16(*)[65])smem;
        int local = bid - 1792;
        int m0 = (local & 31) * 64, b = local >> 5;
        int c = tid & 63, g = tid >> 6;
#pragma unroll
        for (int r = 0; r < 16; ++r) {
            int mm = g * 16 + r;
            t[mm][c] = f2bf(x[((size_t)b * 2048 + m0 + mm) * 64 + c]);
        }
        __syncthreads();
#pragma unroll
        for (int r = 0; r < 16; ++r) {
            int cc = g * 16 + r;
            xtT[((size_t)b * 64 + cc) * 2048 + m0 + c] = t[c][cc];
        }
        if (mode) {
#pragma unroll
            for (int r = 0; r < 16; ++r) {
                int mm = g * 16 + r;
                xn[((size_t)(m0 + mm)) * 2048 + b * 64 + c] = t[mm][c];
            }
        }
    } else if (bid < 2832) {
        // ---- Wp Chebyshev combo, coalesced (o=lane, ki wave-uniform)
        float (*tw)[193] = (float(*)[193])smem;
        const int d = bid - 2816;
        const float* base = Wp + (size_t)d * 12288;    // [k][i][o]
        const int o = tid & 63, seg = tid >> 6;        // seg 0..3
#pragma unroll
        for (int j = 0; j < 48; ++j) {
            int ki = seg * 48 + j;
            int k = ki >> 6, i = ki & 63;              // wave-uniform
            float v;
            if (k == 0)      v = base[i * 64 + o] - base[8192 + i * 64 + o];
            else if (k == 1) v = base[4096 + i * 64 + o];
            else             v = 2.f * base[8192 + i * 64 + o];
            tw[o][ki] = v;
        }
        __syncthreads();
#pragma unroll
        for (int it = 0; it < 12; ++it) {
            int idx = tid + it * 256;
            int oo = idx / 48, q = idx - oo * 48;      // q in [0,48)
            float v0 = tw[oo][q * 4], v1 = tw[oo][q * 4 + 1];
            float v2 = tw[oo][q * 4 + 2], v3 = tw[oo][q * 4 + 3];
            size_t dst = (size_t)(d * 64 + oo) * 192 + q * 4;
            *(float4*)(Wpbf + dst) = make_float4(v0, v1, v2, v3);
            *(ushort4*)(Wpb + dst) = make_ushort4(f2bf(v0), f2bf(v1), f2bf(v2), f2bf(v3));
        }
    } else {
        // ---- bias = E @ bp
        const int nb = bid - 2832;
#pragma unroll
        for (int it = 0; it < 8; ++it) {
            int idx = tid + it * 256;
            int n = nb * 32 + (idx >> 6), o = idx & 63;
            float s = 0.f;
#pragma unroll
            for (int d = 0; d < 16; ++d) s = fmaf(E[n * 16 + d], bp[d * 64 + o], s);
            bias[(size_t)n * 64 + o] = s;
        }
    }
}

// ---------------------------------------------------------------- rzmid: reduce_z + wgen
// grid (wn): 1792 = [0,1024) reduce_z grid-stride x4 | [1024,1792) wgen
__global__ __launch_bounds__(256)
void rzmid(const u16* __restrict__ p, const u16* __restrict__ Acat,
           u16* __restrict__ S, const float* __restrict__ E,
           const float* __restrict__ Wpbf, u16* __restrict__ Wnb) {
    __shared__ float Es[32 * 16];
    const int bid = blockIdx.x, tid = threadIdx.x;
    if (bid < 1024) {
        const size_t base = ((size_t)bid * 256 + tid) * 4;
        const size_t STRIDE = (size_t)1024 * 256 * 4;
#pragma unroll
        for (int it = 0; it < 4; ++it) {
            size_t j = base + (size_t)it * STRIDE;
            ushort4 p0 = *(const ushort4*)(p + j);
            ushort4 p1 = *(const ushort4*)(p + PSTRIDE + j);
            ushort4 p2 = *(const ushort4*)(p + 2 * PSTRIDE + j);
            ushort4 p3 = *(const ushort4*)(p + 3 * PSTRIDE + j);
            int row = (int)(j >> 11), col = (int)(j & 2047);
            ushort4 sp = *(const ushort4*)(Acat + (size_t)row * 4096 + col);
            ushort4 ad = *(const ushort4*)(Acat + (size_t)row * 4096 + 2048 + col);
            float z0 = bf2f(p0.x) + bf2f(p1.x) + bf2f(p2.x) + bf2f(p3.x);
            float z1 = bf2f(p0.y) + bf2f(p1.y) + bf2f(p2.y) + bf2f(p3.y);
            float z2 = bf2f(p0.z) + bf2f(p1.z) + bf2f(p2.z) + bf2f(p3.z);
            float z3 = bf2f(p0.w) + bf2f(p1.w) + bf2f(p2.w) + bf2f(p3.w);
            float s0 = 1.f / (1.f + __expf(-z0)), s1 = 1.f / (1.f + __expf(-z1));
            float s2 = 1.f / (1.f + __expf(-z2)), s3 = 1.f / (1.f + __expf(-z3));
            ushort4 o = make_ushort4(
                f2bf(s0 * bf2f(ad.x) + (1.f - s0) * bf2f(sp.x)),
                f2bf(s1 * bf2f(ad.y) + (1.f - s1) * bf2f(sp.y)),
                f2bf(s2 * bf2f(ad.z) + (1.f - s2) * bf2f(sp.z)),
                f2bf(s3 * bf2f(ad.w) + (1.f - s3) * bf2f(sp.w)));
            *(ushort4*)(S + j) = o;
        }
    } else {
        const int w = bid - 1024;
        const int c0 = (w % 12) * 1024, n0 = (w / 12) * 32;
        for (int j = tid; j < 512; j += 256) Es[j] = E[(size_t)n0 * 16 + j];
        float4 wf[16];
#pragma unroll
        for (int d = 0; d < 16; ++d)
            wf[d] = *(const float4*)(Wpbf + (size_t)d * 12288 + c0 + tid * 4);
        __syncthreads();
        for (int nl = 0; nl < 32; ++nl) {
            float4 s = make_float4(0.f, 0.f, 0.f, 0.f);
#pragma unroll
            for (int d = 0; d < 16; ++d) {
                float e = Es[nl * 16 + d];
                s.x = fmaf(e, wf[d].x, s.x);
                s.y = fmaf(e, wf[d].y, s.y);
                s.z = fmaf(e, wf[d].z, s.z);
                s.w = fmaf(e, wf[d].w, s.w);
            }
            *(ushort4*)(Wnb + (size_t)(n0 + nl) * 12288 + c0 + tid * 4) =
                make_ushort4(f2bf(s.x), f2bf(s.y), f2bf(s.z), f2bf(s.w));
        }
    }
}

// ---------------------------------------------------------------- GEMM 256x256, BK=64, split-K
__global__ __launch_bounds__(512, 2)
void gemm_bt256(const u16* __restrict__ A, const u16* __restrict__ Bt,
                u16* __restrict__ Cp, int M, int N, int K, int Kh) {
    __shared__ alignas(16) u16 As[2][256 * 64];
    __shared__ alignas(16) u16 Bs[2][256 * 64];
    const int tid = threadIdx.x, lane = tid & 63, wave = tid >> 6;

    const int nbx = gridDim.x, nby = gridDim.y, nbz = gridDim.z;
    const int nwg = nbx * nby * nbz;
    int lin = (blockIdx.z * nby + blockIdx.y) * nbx + blockIdx.x;
    if ((nwg & 7) == 0) lin = (lin & 7) * (nwg >> 3) + (lin >> 3);
    const int bz = lin / (nbx * nby);
    const int r2 = lin - bz * nbx * nby;
    const int by = r2 / nbx, bx = r2 - by * nbx;

    const int m0 = by * 256, n0 = bx * 256;
    const int kbeg = bz * Kh;
    const int NT = Kh >> 6;
    const int wm = (wave >> 2) * 128, wn = (wave & 3) * 64;
    const int ml = lane & 15, c0l = lane >> 4;

    int sI[4], rowI[4], gcI[4];
#pragma unroll
    for (int r = 0; r < 4; ++r) {
        int s = r * 512 + tid;
        sI[r] = s; rowI[r] = s >> 3; gcI[r] = (s & 7) ^ ((s >> 3) & 7);
    }

    f32x4 acc[8][4] = {};
    bf16x8 af[4][2], bv[2][2];

#define LOADA(r_, kt_, buf_) \
    gl_lds16(A + (size_t)(m0 + rowI[r_]) * K + (kt_) + gcI[r_] * 8, \
             &As[buf_][sI[r_] * 8])
#define LOADB(r_, kt_, buf_) \
    gl_lds16(Bt + (size_t)(n0 + rowI[r_]) * K + (kt_) + gcI[r_] * 8, \
             &Bs[buf_][sI[r_] * 8])

#define DSRA(qa_) \
    _Pragma("unroll") \
    for (int i = 0; i < 4; ++i) { \
        const int mr = wm + (qa_) * 64 + i * 16 + ml; \
        _Pragma("unroll") \
        for (int ks = 0; ks < 2; ++ks) \
            af[i][ks] = *(const bf16x8*)(Asc + mr * 64 + (((c0l + ks * 4) ^ (mr & 7)) * 8)); \
    }
#define DSRB(qb_) \
    _Pragma("unroll") \
    for (int j = 0; j < 2; ++j) { \
        const int nr = wn + (qb_) * 32 + j * 16 + ml; \
        _Pragma("unroll") \
        for (int ks = 0; ks < 2; ++ks) \
            bv[j][ks] = *(const bf16x8*)(Bsc + nr * 64 + (((c0l + ks * 4) ^ (nr & 7)) * 8)); \
    }
#define MMQ(io_, jo_) \
    __builtin_amdgcn_s_barrier(); \
    asm volatile("s_waitcnt lgkmcnt(0)" ::: "memory"); \
    __builtin_amdgcn_s_setprio(1); \
    _Pragma("unroll") \
    for (int ks = 0; ks < 2; ++ks) \
        _Pragma("unroll") \
        for (int i = 0; i < 4; ++i) \
            _Pragma("unroll") \
            for (int j = 0; j < 2; ++j) \
                acc[(io_) + i][(jo_) + j] = __builtin_amdgcn_mfma_f32_16x16x32_bf16( \
                    af[i][ks], bv[j][ks], acc[(io_) + i][(jo_) + j], 0, 0, 0); \
    __builtin_amdgcn_s_setprio(0);

#pragma unroll
    for (int r = 0; r < 4; ++r) LOADA(r, kbeg, 0);
#pragma unroll
    for (int r = 0; r < 4; ++r) LOADB(r, kbeg, 0);
    asm volatile("s_waitcnt vmcnt(0)" ::: "memory");
    __builtin_amdgcn_s_barrier();

    for (int t = 0; t < NT - 1; ++t) {
        const int cur = t & 1, nxt = cur ^ 1;
        const u16* Asc = As[cur];
        const u16* Bsc = Bs[cur];
        const int k1 = kbeg + (t + 1) * 64;

        DSRA(0); DSRB(0);
        LOADB(0, k1, nxt); LOADB(1, k1, nxt);
        MMQ(0, 0);
        __builtin_amdgcn_s_barrier();

        DSRB(1);
        LOADB(2, k1, nxt); LOADB(3, k1, nxt);
        MMQ(0, 2);
        asm volatile("s_waitcnt vmcnt(4)" ::: "memory");
        __builtin_amdgcn_s_barrier();

        DSRA(1);
        LOADA(0, k1, nxt); LOADA(2, k1, nxt);
        MMQ(4, 2);
        __builtin_amdgcn_s_barrier();

        DSRB(0);
        LOADA(1, k1, nxt); LOADA(3, k1, nxt);
        MMQ(4, 0);
        asm volatile("s_waitcnt vmcnt(2)" ::: "memory");
        __builtin_amdgcn_s_barrier();
    }

    {
        const int cur = (NT - 1) & 1;
        const u16* Asc = As[cur];
        const u16* Bsc = Bs[cur];

        DSRA(0); DSRB(0);
        MMQ(0, 0);
        __builtin_amdgcn_s_barrier();

        DSRB(1);
        MMQ(0, 2);
        asm volatile("s_waitcnt vmcnt(0)" ::: "memory");
        __builtin_amdgcn_s_barrier();

        DSRA(1);
        MMQ(4, 2);
        __builtin_amdgcn_s_barrier();

        DSRB(0);
        MMQ(4, 0);
    }

#undef LOADA
#undef LOADB
#undef DSRA
#undef DSRB
#undef MMQ

    const int col_l = lane & 15, rl = (lane >> 4) * 4;
    u16* Cz = Cp + (size_t)bz * M * N;
#pragma unroll
    for (int i = 0; i < 8; ++i)
#pragma unroll
        for (int j = 0; j < 4; ++j)
#pragma unroll
            for (int r = 0; r < 4; ++r) {
                int row = m0 + wm + i * 16 + rl + r;
                int col = n0 + wn + j * 16 + col_l;
                Cz[(size_t)row * N + col] = f2bf(acc[i][j][r]);
            }
}

// ---------------------------------------------------------------- reduceT
__global__ __launch_bounds__(256)
void reduceT(const u16* __restrict__ p, u16* __restrict__ xg1o,
             u16* __restrict__ xg1T, int mode) {
    __shared__ u16 t[64][68];
    int bx = blockIdx.x * 64, by = blockIdx.y * 64;
    int cg = threadIdx.x & 15, rg = threadIdx.x >> 4;
    int b = bx >> 6;
#pragma unroll
    for (int rr = 0; rr < 4; ++rr) {
        int row = rg * 4 + rr;
        size_t idx = (size_t)(by + row) * 2048 + bx + cg * 4;
        ushort4 q0 = *(const ushort4*)(p + idx);
        ushort4 q1 = *(const ushort4*)(p + PSTRIDE + idx);
        ushort4 q2 = *(const ushort4*)(p + 2 * PSTRIDE + idx);
        ushort4 q3 = *(const ushort4*)(p + 3 * PSTRIDE + idx);
        ushort4 v = make_ushort4(
            f2bf(bf2f(q0.x) + bf2f(q1.x) + bf2f(q2.x) + bf2f(q3.x)),
            f2bf(bf2f(q0.y) + bf2f(q1.y) + bf2f(q2.y) + bf2f(q3.y)),
            f2bf(bf2f(q0.z) + bf2f(q1.z) + bf2f(q2.z) + bf2f(q3.z)),
            f2bf(bf2f(q0.w) + bf2f(q1.w) + bf2f(q2.w) + bf2f(q3.w)));
        if (mode) *(ushort4*)(xg1o + idx) = v;
        else      *(ushort4*)(xg1o + ((size_t)b * 2048 + by + row) * 64 + cg * 4) = v;
        *(ushort4*)(&t[row][cg * 4]) = v;
    }
    __syncthreads();
    int c = threadIdx.x & 63, g = threadIdx.x >> 6;
#pragma unroll
    for (int r = 0; r < 16; ++r) {
        int row = g * 16 + r;
        xg1T[(size_t)(bx + row) * 2048 + by + c] = t[c][row];
    }
}

// ---------------------------------------------------------------- gconv_wn (Wn mode)
__global__ __launch_bounds__(256, 4)
void gconv_wn(const u16* __restrict__ xn, const u16* __restrict__ xg1n,
              const u16* __restrict__ p, const u16* __restrict__ Wnb,
              const float* __restrict__ bias, float* __restrict__ out) {
    __shared__ alignas(16) u16 As[32 * 192];
    __shared__ alignas(16) u16 Bs[64 * 192];
    const int n = blockIdx.x, tid = threadIdx.x;
    const int lane = tid & 63, wave = tid >> 6;
    const int wn2 = wave * 16;
    const int ml = lane & 15, c0l = lane >> 4;
    const int col = lane & 15, rl = (lane >> 4) * 4;

#pragma unroll
    for (int it = 0; it < 6; ++it) {
        int s = tid + it * 256;
        int row = s / 24, sc = s - row * 24;
        int gc = (sc & 24) | ((sc ^ row) & 7);
        gl_lds16(Wnb + (size_t)n * 12288 + (size_t)row * 192 + gc * 8, Bs + (size_t)s * 8);
    }
#pragma unroll
    for (int it = 0; it < 3; ++it) {
        int s = tid + it * 256;
        int row = s / 24, sc = s - row * 24;
        int gc = (sc & 24) | ((sc ^ row) & 7);
        u16x8 v;
        if (gc < 8) {
            v = *(const u16x8*)(xn + (size_t)n * 2048 + row * 64 + (gc & 7) * 8);
        } else if (gc < 16) {
            v = *(const u16x8*)(xg1n + (size_t)n * 2048 + row * 64 + (gc & 7) * 8);
        } else {
            const u16* pp = p + (size_t)n * 2048 + row * 64 + (gc & 7) * 8;
            u16x8 q0 = *(const u16x8*)pp;
            u16x8 q1 = *(const u16x8*)(pp + PSTRIDE);
            u16x8 q2 = *(const u16x8*)(pp + 2 * PSTRIDE);
            u16x8 q3 = *(const u16x8*)(pp + 3 * PSTRIDE);
#pragma unroll
            for (int tt = 0; tt < 8; ++tt)
                v[tt] = f2bf(bf2f(q0[tt]) + bf2f(q1[tt]) + bf2f(q2[tt]) + bf2f(q3[tt]));
        }
        *(u16x8*)(As + (size_t)s * 8) = v;
    }
    float bv0 = bias[(size_t)n * 64 + wn2 + col];
    f32x4 acc[2];
#pragma unroll
    for (int mt = 0; mt < 2; ++mt)
#pragma unroll
        for (int r = 0; r < 4; ++r) acc[mt][r] = bv0;
    __syncthreads();

#pragma unroll
    for (int ks = 0; ks < 6; ++ks) {
        int c = c0l + ks * 4;
        int o = wn2 + ml;
        bf16x8 bfrag = *(const bf16x8*)(Bs + (o * 24 + ((c & 24) | ((c ^ (o & 7)) & 7))) * 8);
#pragma unroll
        for (int mt = 0; mt < 2; ++mt) {
            int m = mt * 16 + ml;
            bf16x8 afrag = *(const bf16x8*)(As + (m * 24 + ((c & 24) | ((c ^ (m & 7)) & 7))) * 8);
            acc[mt] = __builtin_amdgcn_mfma_f32_16x16x32_bf16(afrag, bfrag, acc[mt], 0, 0, 0);
        }
    }
#pragma unroll
    for (int mt = 0; mt < 2; ++mt)
#pragma unroll
        for (int r = 0; r < 4; ++r) {
            int b = mt * 16 + rl + r;
            out[((size_t)b * 2048 + n) * 64 + wn2 + col] = acc[mt][r];
        }
}

// ---------------------------------------------------------------- gconv_mfma (legacy fallback)
__global__ __launch_bounds__(256, 2)
void gconv_mfma(const float* __restrict__ x, const u16* __restrict__ xg1,
                const u16* __restrict__ p, const u16* __restrict__ Wpb,
                const float* __restrict__ bias, const float* __restrict__ E,
                float* __restrict__ out) {
    __shared__ alignas(16) float El[16 * 128];
    const int tid = threadIdx.x, lane = tid & 63, wave = tid >> 6;
    const int m0 = blockIdx.x * 128, nb = m0 & 2047, bB = m0 >> 11;
    const int wm = (wave >> 1) * 64, wn = (wave & 1) * 32;
    const int ml = lane & 15, c0l = lane >> 4;
    const int col_l = lane & 15, rl = (lane >> 4) * 4;

#pragma unroll
    for (int it = 0; it < 8; ++it) {
        int idx = tid + it * 256;
        El[idx] = E[(size_t)(nb + (idx & 127)) * 16 + (idx >> 7)];
    }
    __syncthreads();

    bf16x8 af[4][6];
#pragma unroll
    for (int i = 0; i < 4; ++i) {
        const int row = m0 + wm + i * 16 + ml;
        const int n = row & 2047;
#pragma unroll
        for (int ks = 0; ks < 2; ++ks) {
            const float* xp = x + (size_t)row * 64 + (c0l + ks * 4) * 8;
            float4 a = *(const float4*)xp, b4 = *(const float4*)(xp + 4);
            u16x8 v;
            v[0] = f2bf(a.x);  v[1] = f2bf(a.y);  v[2] = f2bf(a.z);  v[3] = f2bf(a.w);
            v[4] = f2bf(b4.x); v[5] = f2bf(b4.y); v[6] = f2bf(b4.z); v[7] = f2bf(b4.w);
            af[i][ks] = __builtin_bit_cast(bf16x8, v);
        }
#pragma unroll
        for (int ks = 2; ks < 4; ++ks)
            af[i][ks] = *(const bf16x8*)(xg1 + (size_t)row * 64 + (c0l + ks * 4 - 8) * 8);
#pragma unroll
        for (int ks = 4; ks < 6; ++ks) {
            const u16* pp = p + (size_t)n * 2048 + bB * 64 + (c0l + ks * 4 - 16) * 8;
            u16x8 q0 = *(const u16x8*)pp;
            u16x8 q1 = *(const u16x8*)(pp + PSTRIDE);
            u16x8 q2 = *(const u16x8*)(pp + 2 * PSTRIDE);
            u16x8 q3 = *(const u16x8*)(pp + 3 * PSTRIDE);
            u16x8 v;
#pragma unroll
            for (int tt = 0; tt < 8; ++tt)
                v[tt] = f2bf(bf2f(q0[tt]) + bf2f(q1[tt]) + bf2f(q2[tt]) + bf2f(q3[tt]));
            af[i][ks] = __builtin_bit_cast(bf16x8, v);
        }
    }

    f32x4 oacc[4][2];
#pragma unroll
    for (int i = 0; i < 4; ++i)
#pragma unroll
        for (int j = 0; j < 2; ++j)
#pragma unroll
            for (int r = 0; r < 4; ++r)
                oacc[i][j][r] = bias[(size_t)(nb + wm + i * 16 + rl + r) * 64 + wn + j * 16 + col_l];

#pragma unroll 2
    for (int d = 0; d < 16; ++d) {
        bf16x8 bv[2][6];
#pragma unroll
        for (int j = 0; j < 2; ++j) {
            const u16* wp = Wpb + (size_t)(d * 64 + wn + j * 16 + ml) * 192 + c0l * 8;
#pragma unroll
            for (int ks = 0; ks < 6; ++ks)
                bv[j][ks] = *(const bf16x8*)(wp + ks * 32);
        }
        f32x4 tmp[4][2] = {};
#pragma unroll
        for (int ks = 0; ks < 6; ++ks)
#pragma unroll
            for (int i = 0; i < 4; ++i)
#pragma unroll
                for (int j = 0; j < 2; ++j)
                    tmp[i][j] = __builtin_amdgcn_mfma_f32_16x16x32_bf16(af[i][ks], bv[j][ks], tmp[i][j], 0, 0, 0);
#pragma unroll
        for (int i = 0; i < 4; ++i) {
            f32x4 ev = *(const f32x4*)(El + d * 128 + wm + i * 16 + rl);
#pragma unroll
            for (int r = 0; r < 4; ++r)
#pragma unroll
                for (int j = 0; j < 2; ++j)
                    oacc[i][j][r] = fmaf(ev[r], tmp[i][j][r], oacc[i][j][r]);
        }
    }
#pragma unroll
    for (int i = 0; i < 4; ++i)
#pragma unroll
        for (int j = 0; j < 2; ++j)
#pragma unroll
            for (int r = 0; r < 4; ++r)
                out[(size_t)(m0 + wm + i * 16 + rl + r) * 64 + wn + j * 16 + col_l] = oacc[i][j][r];
}

// ---------------------------------------------------------------- launch
extern "C" void kernel_launch(void* const* d_in, const int* in_sizes, int n_in,
                              void* d_out, int out_size, void* d_ws, size_t ws_size,
                              hipStream_t stream) {
    const float* x   = (const float*)d_in[0];
    const float* E   = (const float*)d_in[1];
    const float* adj = (const float*)d_in[2];
    const float* Wp  = (const float*)d_in[3];
    const float* bp  = (const float*)d_in[4];
    const float* saw = (const float*)d_in[5];
    float* out = (float*)d_out;

    char* ws = (char*)d_ws;
    const size_t MB = 1u << 20;
    const int wn_mode = (ws_size >= 140 * MB) ? 1 : 0;

    u16*   Acat  = (u16*)(ws);                  // [0,16M)
    u16*   sawb  = (u16*)(ws + 16 * MB);        // [16,32M)
    u16*   XtT   = (u16*)(ws + 32 * MB);        // [32,40M)
    u16*   Wpb   = (u16*)(ws + 40 * MB);        // [40,40.4M) bf16
    float* bias  = (float*)(ws + 41 * MB);      // [41,41.5M)
    float* Wpbf  = (float*)(ws + 42 * MB);      // [42,42.8M) fp32
    u16*   part  = (u16*)(ws + 48 * MB);        // [48,80M)
    u16*   S_bf  = (u16*)(ws + 16 * MB);        // [16,24M)
    u16*   xg1T  = (u16*)(ws + 24 * MB);        // [24,32M)
    u16*   xg1o  = (u16*)(ws);                  // [0,8M)
    u16*   xn    = (u16*)(ws + 80 * MB);        // [80,88M)   wn only
    u16*   Wnb   = (u16*)(ws + 88 * MB);        // [88,138.4M) wn only

    preA<<<2896, 256, 0, stream>>>(E, adj, saw, x, Wp, bp, Acat, sawb, XtT,
                                   Wpb, Wpbf, bias, xn, wn_mode);

    gemm_bt256<<<dim3(8, 8, 4), 512, 0, stream>>>(Acat, sawb, part, 2048, 2048, 4096, 1024);
    rzmid<<<wn_mode ? 1792 : 1024, 256, 0, stream>>>(part, Acat, S_bf, E, Wpbf, Wnb);
    gemm_bt256<<<dim3(8, 8, 4), 512, 0, stream>>>(S_bf, XtT, part, 2048, 2048, 2048, 512);
    reduceT<<<dim3(32, 32), 256, 0, stream>>>(part, xg1o, xg1T, wn_mode);
    gemm_bt256<<<dim3(8, 8, 4), 512, 0, stream>>>(S_bf, xg1T, part, 2048, 2048, 2048, 512);

    if (wn_mode)
        gconv_wn<<<2048, 256, 0, stream>>>(xn, xg1o, part, Wnb, bias, out);
    else
        gconv_mfma<<<512, 256, 0, stream>>>(x, xg1o, part, Wpb, bias, E, out);
}

// Round 7
// 274.734 us; speedup vs baseline: 1.0437x; 1.0132x over previous
//
#include <hip/hip_runtime.h>

// AVWGCN: B=32, N=2048, C=64, O=64, K=3, D=16
// R20 changes vs R19 (preA 55us at 10% occupancy: the 64KB static smem union caps ALL
// 2896 blocks at 2/CU, starving the BW-bound conv segment -> 1.6TB/s on 87MB):
//  - zsm segment: Et staged in 4 phases of 4 d-rows (Et4[4][2048] = 32KB), accumulation
//    order still d=0..15 ascending -> bit-identical.
//  - Wp segment: 2-pass transpose tw[64][97] (24.8KB), halves ki 0..95 / 96..191.
//  - smem union 64KB -> 32KB -> 5 blocks/CU (20 waves/CU).
// Everything else identical to R19 (7 dispatches, counted-vmcnt gemm_bt256, rzmid).

typedef unsigned short u16;
typedef float f32x4 __attribute__((ext_vector_type(4)));
typedef __bf16 bf16x8 __attribute__((ext_vector_type(8)));
typedef unsigned short u16x8 __attribute__((ext_vector_type(8)));

#define PSTRIDE ((size_t)2048 * 2048)

__device__ __forceinline__ u16 f2bf(float f) {
    unsigned u = __float_as_uint(f);
    u += 0x7FFFu + ((u >> 16) & 1u);   // RNE
    return (u16)(u >> 16);
}
__device__ __forceinline__ float bf2f(u16 h) {
    return __uint_as_float((unsigned)h << 16);
}
__device__ __forceinline__ void gl_lds16(const void* g, void* l) {
    __builtin_amdgcn_global_load_lds(
        (const __attribute__((address_space(1))) unsigned*)g,
        (__attribute__((address_space(3))) unsigned*)l, 16, 0, 0);
}

// ---------------------------------------------------------------- preA (fully fused)
// grid 2896: [0,256) zsm | [256,1792) adj+saw conv | [1792,2816) x-T
//            | [2816,2832) Wp coalesced | [2832,2896) bias
__global__ __launch_bounds__(256)
void preA(const float* __restrict__ E, const float* __restrict__ adj,
          const float* __restrict__ saw, const float* __restrict__ x,
          const float* __restrict__ Wp, const float* __restrict__ bp,
          u16* __restrict__ Acat, u16* __restrict__ sawb, u16* __restrict__ xtT,
          u16* __restrict__ Wpb, float* __restrict__ Wpbf,
          float* __restrict__ bias, u16* __restrict__ xn, int mode) {
    __shared__ __align__(16) char smem[32768];
    const int bid = blockIdx.x, tid = threadIdx.x;

    if (bid < 256) {
        // ---- zsm: softmax(relu(E@E^T)) rows [8b,8b+8) -> Acat bf16, 4-phase Et
        float* Et4 = (float*)smem;            // [4][2048] fp32 = 32KB
        const int r0 = bid * 8;
        float z[8][8] = {};
#pragma unroll
        for (int ph = 0; ph < 4; ++ph) {
            if (ph) __syncthreads();          // all reads of previous phase done
#pragma unroll
            for (int k = 0; k < 8; ++k) {
                const int n = tid + 256 * k;
                float4 e = ((const float4*)(E + (size_t)n * 16))[ph];
                Et4[0 * 2048 + n] = e.x; Et4[1 * 2048 + n] = e.y;
                Et4[2 * 2048 + n] = e.z; Et4[3 * 2048 + n] = e.w;
            }
            __syncthreads();
#pragma unroll
            for (int d = 0; d < 4; ++d) {     // global d = ph*4+d, ascending (bit-identical)
                const float* row = Et4 + d * 2048;
                float ev[8];
#pragma unroll
                for (int k = 0; k < 8; ++k) ev[k] = row[tid + 256 * k];
#pragma unroll
                for (int r = 0; r < 8; ++r) {
                    float e = row[r0 + r];    // broadcast
#pragma unroll
                    for (int k = 0; k < 8; ++k) z[r][k] = fmaf(e, ev[k], z[r][k]);
                }
            }
        }
        __syncthreads();                       // Et4 dead; reuse smem for reductions
        float (*redm)[8] = (float(*)[8])smem;
        float (*reds)[8] = (float(*)[8])(smem + 256);

        float mr[8];
#pragma unroll
        for (int r = 0; r < 8; ++r) {
            float m = 0.f;
#pragma unroll
            for (int k = 0; k < 8; ++k) { z[r][k] = fmaxf(z[r][k], 0.f); m = fmaxf(m, z[r][k]); }
            mr[r] = m;
        }
#pragma unroll
        for (int off = 32; off; off >>= 1)
#pragma unroll
            for (int r = 0; r < 8; ++r) mr[r] = fmaxf(mr[r], __shfl_xor(mr[r], off, 64));
        if ((tid & 63) == 0) {
#pragma unroll
            for (int r = 0; r < 8; ++r) redm[tid >> 6][r] = mr[r];
        }
        __syncthreads();
#pragma unroll
        for (int r = 0; r < 8; ++r)
            mr[r] = fmaxf(fmaxf(redm[0][r], redm[1][r]), fmaxf(redm[2][r], redm[3][r]));
        float sr[8];
#pragma unroll
        for (int r = 0; r < 8; ++r) {
            float s = 0.f;
#pragma unroll
            for (int k = 0; k < 8; ++k) { z[r][k] = __expf(z[r][k] - mr[r]); s += z[r][k]; }
            sr[r] = s;
        }
#pragma unroll
        for (int off = 32; off; off >>= 1)
#pragma unroll
            for (int r = 0; r < 8; ++r) sr[r] += __shfl_xor(sr[r], off, 64);
        if ((tid & 63) == 0) {
#pragma unroll
            for (int r = 0; r < 8; ++r) reds[tid >> 6][r] = sr[r];
        }
        __syncthreads();
#pragma unroll
        for (int r = 0; r < 8; ++r) {
            float inv = 1.f / (reds[0][r] + reds[1][r] + reds[2][r] + reds[3][r]);
            u16* orow = Acat + (size_t)(r0 + r) * 4096;
#pragma unroll
            for (int k = 0; k < 8; ++k) orow[tid + 256 * k] = f2bf(z[r][k] * inv);
        }
    } else if (bid < 1792) {
        // ---- adj (1M float4) + saw (2M float4) -> bf16, batched grid-stride
        const size_t NADJ = 1048576, STRIDE = (size_t)1536 * 256;
        const size_t e0 = (size_t)(bid - 256) * 256 + tid;
        float4 v[8];
#pragma unroll
        for (int it = 0; it < 8; ++it) {
            size_t idx = e0 + (size_t)it * STRIDE;
            const float* src = (idx < NADJ) ? (adj + idx * 4) : (saw + (idx - NADJ) * 4);
            v[it] = *(const float4*)src;
        }
#pragma unroll
        for (int it = 0; it < 8; ++it) {
            size_t idx = e0 + (size_t)it * STRIDE;
            ushort4 o = make_ushort4(f2bf(v[it].x), f2bf(v[it].y), f2bf(v[it].z), f2bf(v[it].w));
            if (idx < NADJ) {
                size_t j = idx * 4;
                int n = (int)(j >> 11), c = (int)(j & 2047);
                *(ushort4*)(Acat + (size_t)n * 4096 + 2048 + c) = o;
            } else {
                *(ushort4*)(sawb + (idx - NADJ) * 4) = o;
            }
        }
    } else if (bid < 2816) {
        // ---- x transpose (+xn in wn mode)
        u16 (*t)[65] = (u16(*)[65])smem;
        int local = bid - 1792;
        int m0 = (local & 31) * 64, b = local >> 5;
        int c = tid & 63, g = tid >> 6;
#pragma unroll
        for (int r = 0; r < 16; ++r) {
            int mm = g * 16 + r;
            t[mm][c] = f2bf(x[((size_t)b * 2048 + m0 + mm) * 64 + c]);
        }
        __syncthreads();
#pragma unroll
        for (int r = 0; r < 16; ++r) {
            int cc = g * 16 + r;
            xtT[((size_t)b * 64 + cc) * 2048 + m0 + c] = t[c][cc];
        }
        if (mode) {
#pragma unroll
            for (int r = 0; r < 16; ++r) {
                int mm = g * 16 + r;
                xn[((size_t)(m0 + mm)) * 2048 + b * 64 + c] = t[mm][c];
            }
        }
    } else if (bid < 2832) {
        // ---- Wp Chebyshev combo, coalesced, 2-pass (half ki range per pass)
        float (*tw)[97] = (float(*)[97])smem;   // 64*97*4 = 24.8KB
        const int d = bid - 2816;
        const float* base = Wp + (size_t)d * 12288;    // [k][i][o]
        const int o = tid & 63, seg = tid >> 6;        // seg 0..3
#pragma unroll
        for (int half = 0; half < 2; ++half) {
            if (half) __syncthreads();
#pragma unroll
            for (int j = 0; j < 24; ++j) {
                int ki = half * 96 + seg * 24 + j;
                int k = ki >> 6, i = ki & 63;          // wave-uniform
                float v;
                if (k == 0)      v = base[i * 64 + o] - base[8192 + i * 64 + o];
                else if (k == 1) v = base[4096 + i * 64 + o];
                else             v = 2.f * base[8192 + i * 64 + o];
                tw[o][ki - half * 96] = v;
            }
            __syncthreads();
#pragma unroll
            for (int it = 0; it < 6; ++it) {
                int idx = tid + it * 256;
                int oo = idx / 24, q = idx - oo * 24;  // q in [0,24)
                float v0 = tw[oo][q * 4], v1 = tw[oo][q * 4 + 1];
                float v2 = tw[oo][q * 4 + 2], v3 = tw[oo][q * 4 + 3];
                size_t dst = (size_t)(d * 64 + oo) * 192 + half * 96 + q * 4;
                *(float4*)(Wpbf + dst) = make_float4(v0, v1, v2, v3);
                *(ushort4*)(Wpb + dst) = make_ushort4(f2bf(v0), f2bf(v1), f2bf(v2), f2bf(v3));
            }
        }
    } else {
        // ---- bias = E @ bp
        const int nb = bid - 2832;
#pragma unroll
        for (int it = 0; it < 8; ++it) {
            int idx = tid + it * 256;
            int n = nb * 32 + (idx >> 6), o = idx & 63;
            float s = 0.f;
#pragma unroll
            for (int d = 0; d < 16; ++d) s = fmaf(E[n * 16 + d], bp[d * 64 + o], s);
            bias[(size_t)n * 64 + o] = s;
        }
    }
}

// ---------------------------------------------------------------- rzmid: reduce_z + wgen
// grid (wn): 1792 = [0,1024) reduce_z grid-stride x4 | [1024,1792) wgen
__global__ __launch_bounds__(256)
void rzmid(const u16* __restrict__ p, const u16* __restrict__ Acat,
           u16* __restrict__ S, const float* __restrict__ E,
           const float* __restrict__ Wpbf, u16* __restrict__ Wnb) {
    __shared__ float Es[32 * 16];
    const int bid = blockIdx.x, tid = threadIdx.x;
    if (bid < 1024) {
        const size_t base = ((size_t)bid * 256 + tid) * 4;
        const size_t STRIDE = (size_t)1024 * 256 * 4;
#pragma unroll
        for (int it = 0; it < 4; ++it) {
            size_t j = base + (size_t)it * STRIDE;
            ushort4 p0 = *(const ushort4*)(p + j);
            ushort4 p1 = *(const ushort4*)(p + PSTRIDE + j);
            ushort4 p2 = *(const ushort4*)(p + 2 * PSTRIDE + j);
            ushort4 p3 = *(const ushort4*)(p + 3 * PSTRIDE + j);
            int row = (int)(j >> 11), col = (int)(j & 2047);
            ushort4 sp = *(const ushort4*)(Acat + (size_t)row * 4096 + col);
            ushort4 ad = *(const ushort4*)(Acat + (size_t)row * 4096 + 2048 + col);
            float z0 = bf2f(p0.x) + bf2f(p1.x) + bf2f(p2.x) + bf2f(p3.x);
            float z1 = bf2f(p0.y) + bf2f(p1.y) + bf2f(p2.y) + bf2f(p3.y);
            float z2 = bf2f(p0.z) + bf2f(p1.z) + bf2f(p2.z) + bf2f(p3.z);
            float z3 = bf2f(p0.w) + bf2f(p1.w) + bf2f(p2.w) + bf2f(p3.w);
            float s0 = 1.f / (1.f + __expf(-z0)), s1 = 1.f / (1.f + __expf(-z1));
            float s2 = 1.f / (1.f + __expf(-z2)), s3 = 1.f / (1.f + __expf(-z3));
            ushort4 o = make_ushort4(
                f2bf(s0 * bf2f(ad.x) + (1.f - s0) * bf2f(sp.x)),
                f2bf(s1 * bf2f(ad.y) + (1.f - s1) * bf2f(sp.y)),
                f2bf(s2 * bf2f(ad.z) + (1.f - s2) * bf2f(sp.z)),
                f2bf(s3 * bf2f(ad.w) + (1.f - s3) * bf2f(sp.w)));
            *(ushort4*)(S + j) = o;
        }
    } else {
        const int w = bid - 1024;
        const int c0 = (w % 12) * 1024, n0 = (w / 12) * 32;
        for (int j = tid; j < 512; j += 256) Es[j] = E[(size_t)n0 * 16 + j];
        float4 wf[16];
#pragma unroll
        for (int d = 0; d < 16; ++d)
            wf[d] = *(const float4*)(Wpbf + (size_t)d * 12288 + c0 + tid * 4);
        __syncthreads();
        for (int nl = 0; nl < 32; ++nl) {
            float4 s = make_float4(0.f, 0.f, 0.f, 0.f);
#pragma unroll
            for (int d = 0; d < 16; ++d) {
                float e = Es[nl * 16 + d];
                s.x = fmaf(e, wf[d].x, s.x);
                s.y = fmaf(e, wf[d].y, s.y);
                s.z = fmaf(e, wf[d].z, s.z);
                s.w = fmaf(e, wf[d].w, s.w);
            }
            *(ushort4*)(Wnb + (size_t)(n0 + nl) * 12288 + c0 + tid * 4) =
                make_ushort4(f2bf(s.x), f2bf(s.y), f2bf(s.z), f2bf(s.w));
        }
    }
}

// ---------------------------------------------------------------- GEMM 256x256, BK=64, split-K
__global__ __launch_bounds__(512, 2)
void gemm_bt256(const u16* __restrict__ A, const u16* __restrict__ Bt,
                u16* __restrict__ Cp, int M, int N, int K, int Kh) {
    __shared__ alignas(16) u16 As[2][256 * 64];
    __shared__ alignas(16) u16 Bs[2][256 * 64];
    const int tid = threadIdx.x, lane = tid & 63, wave = tid >> 6;

    const int nbx = gridDim.x, nby = gridDim.y, nbz = gridDim.z;
    const int nwg = nbx * nby * nbz;
    int lin = (blockIdx.z * nby + blockIdx.y) * nbx + blockIdx.x;
    if ((nwg & 7) == 0) lin = (lin & 7) * (nwg >> 3) + (lin >> 3);
    const int bz = lin / (nbx * nby);
    const int r2 = lin - bz * nbx * nby;
    const int by = r2 / nbx, bx = r2 - by * nbx;

    const int m0 = by * 256, n0 = bx * 256;
    const int kbeg = bz * Kh;
    const int NT = Kh >> 6;
    const int wm = (wave >> 2) * 128, wn = (wave & 3) * 64;
    const int ml = lane & 15, c0l = lane >> 4;

    int sI[4], rowI[4], gcI[4];
#pragma unroll
    for (int r = 0; r < 4; ++r) {
        int s = r * 512 + tid;
        sI[r] = s; rowI[r] = s >> 3; gcI[r] = (s & 7) ^ ((s >> 3) & 7);
    }

    f32x4 acc[8][4] = {};
    bf16x8 af[4][2], bv[2][2];

#define LOADA(r_, kt_, buf_) \
    gl_lds16(A + (size_t)(m0 + rowI[r_]) * K + (kt_) + gcI[r_] * 8, \
             &As[buf_][sI[r_] * 8])
#define LOADB(r_, kt_, buf_) \
    gl_lds16(Bt + (size_t)(n0 + rowI[r_]) * K + (kt_) + gcI[r_] * 8, \
             &Bs[buf_][sI[r_] * 8])

#define DSRA(qa_) \
    _Pragma("unroll") \
    for (int i = 0; i < 4; ++i) { \
        const int mr = wm + (qa_) * 64 + i * 16 + ml; \
        _Pragma("unroll") \
        for (int ks = 0; ks < 2; ++ks) \
            af[i][ks] = *(const bf16x8*)(Asc + mr * 64 + (((c0l + ks * 4) ^ (mr & 7)) * 8)); \
    }
#define DSRB(qb_) \
    _Pragma("unroll") \
    for (int j = 0; j < 2; ++j) { \
        const int nr = wn + (qb_) * 32 + j * 16 + ml; \
        _Pragma("unroll") \
        for (int ks = 0; ks < 2; ++ks) \
            bv[j][ks] = *(const bf16x8*)(Bsc + nr * 64 + (((c0l + ks * 4) ^ (nr & 7)) * 8)); \
    }
#define MMQ(io_, jo_) \
    __builtin_amdgcn_s_barrier(); \
    asm volatile("s_waitcnt lgkmcnt(0)" ::: "memory"); \
    __builtin_amdgcn_s_setprio(1); \
    _Pragma("unroll") \
    for (int ks = 0; ks < 2; ++ks) \
        _Pragma("unroll") \
        for (int i = 0; i < 4; ++i) \
            _Pragma("unroll") \
            for (int j = 0; j < 2; ++j) \
                acc[(io_) + i][(jo_) + j] = __builtin_amdgcn_mfma_f32_16x16x32_bf16( \
                    af[i][ks], bv[j][ks], acc[(io_) + i][(jo_) + j], 0, 0, 0); \
    __builtin_amdgcn_s_setprio(0);

#pragma unroll
    for (int r = 0; r < 4; ++r) LOADA(r, kbeg, 0);
#pragma unroll
    for (int r = 0; r < 4; ++r) LOADB(r, kbeg, 0);
    asm volatile("s_waitcnt vmcnt(0)" ::: "memory");
    __builtin_amdgcn_s_barrier();

    for (int t = 0; t < NT - 1; ++t) {
        const int cur = t & 1, nxt = cur ^ 1;
        const u16* Asc = As[cur];
        const u16* Bsc = Bs[cur];
        const int k1 = kbeg + (t + 1) * 64;

        DSRA(0); DSRB(0);
        LOADB(0, k1, nxt); LOADB(1, k1, nxt);
        MMQ(0, 0);
        __builtin_amdgcn_s_barrier();

        DSRB(1);
        LOADB(2, k1, nxt); LOADB(3, k1, nxt);
        MMQ(0, 2);
        asm volatile("s_waitcnt vmcnt(4)" ::: "memory");
        __builtin_amdgcn_s_barrier();

        DSRA(1);
        LOADA(0, k1, nxt); LOADA(2, k1, nxt);
        MMQ(4, 2);
        __builtin_amdgcn_s_barrier();

        DSRB(0);
        LOADA(1, k1, nxt); LOADA(3, k1, nxt);
        MMQ(4, 0);
        asm volatile("s_waitcnt vmcnt(2)" ::: "memory");
        __builtin_amdgcn_s_barrier();
    }

    {
        const int cur = (NT - 1) & 1;
        const u16* Asc = As[cur];
        const u16* Bsc = Bs[cur];

        DSRA(0); DSRB(0);
        MMQ(0, 0);
        __builtin_amdgcn_s_barrier();

        DSRB(1);
        MMQ(0, 2);
        asm volatile("s_waitcnt vmcnt(0)" ::: "memory");
        __builtin_amdgcn_s_barrier();

        DSRA(1);
        MMQ(4, 2);
        __builtin_amdgcn_s_barrier();

        DSRB(0);
        MMQ(4, 0);
    }

#undef LOADA
#undef LOADB
#undef DSRA
#undef DSRB
#undef MMQ

    const int col_l = lane & 15, rl = (lane >> 4) * 4;
    u16* Cz = Cp + (size_t)bz * M * N;
#pragma unroll
    for (int i = 0; i < 8; ++i)
#pragma unroll
        for (int j = 0; j < 4; ++j)
#pragma unroll
            for (int r = 0; r < 4; ++r) {
                int row = m0 + wm + i * 16 + rl + r;
                int col = n0 + wn + j * 16 + col_l;
                Cz[(size_t)row * N + col] = f2bf(acc[i][j][r]);
            }
}

// ---------------------------------------------------------------- reduceT
__global__ __launch_bounds__(256)
void reduceT(const u16* __restrict__ p, u16* __restrict__ xg1o,
             u16* __restrict__ xg1T, int mode) {
    __shared__ u16 t[64][68];
    int bx = blockIdx.x * 64, by = blockIdx.y * 64;
    int cg = threadIdx.x & 15, rg = threadIdx.x >> 4;
    int b = bx >> 6;
#pragma unroll
    for (int rr = 0; rr < 4; ++rr) {
        int row = rg * 4 + rr;
        size_t idx = (size_t)(by + row) * 2048 + bx + cg * 4;
        ushort4 q0 = *(const ushort4*)(p + idx);
        ushort4 q1 = *(const ushort4*)(p + PSTRIDE + idx);
        ushort4 q2 = *(const ushort4*)(p + 2 * PSTRIDE + idx);
        ushort4 q3 = *(const ushort4*)(p + 3 * PSTRIDE + idx);
        ushort4 v = make_ushort4(
            f2bf(bf2f(q0.x) + bf2f(q1.x) + bf2f(q2.x) + bf2f(q3.x)),
            f2bf(bf2f(q0.y) + bf2f(q1.y) + bf2f(q2.y) + bf2f(q3.y)),
            f2bf(bf2f(q0.z) + bf2f(q1.z) + bf2f(q2.z) + bf2f(q3.z)),
            f2bf(bf2f(q0.w) + bf2f(q1.w) + bf2f(q2.w) + bf2f(q3.w)));
        if (mode) *(ushort4*)(xg1o + idx) = v;
        else      *(ushort4*)(xg1o + ((size_t)b * 2048 + by + row) * 64 + cg * 4) = v;
        *(ushort4*)(&t[row][cg * 4]) = v;
    }
    __syncthreads();
    int c = threadIdx.x & 63, g = threadIdx.x >> 6;
#pragma unroll
    for (int r = 0; r < 16; ++r) {
        int row = g * 16 + r;
        xg1T[(size_t)(bx + row) * 2048 + by + c] = t[c][row];
    }
}

// ---------------------------------------------------------------- gconv_wn (Wn mode)
__global__ __launch_bounds__(256, 4)
void gconv_wn(const u16* __restrict__ xn, const u16* __restrict__ xg1n,
              const u16* __restrict__ p, const u16* __restrict__ Wnb,
              const float* __restrict__ bias, float* __restrict__ out) {
    __shared__ alignas(16) u16 As[32 * 192];
    __shared__ alignas(16) u16 Bs[64 * 192];
    const int n = blockIdx.x, tid = threadIdx.x;
    const int lane = tid & 63, wave = tid >> 6;
    const int wn2 = wave * 16;
    const int ml = lane & 15, c0l = lane >> 4;
    const int col = lane & 15, rl = (lane >> 4) * 4;

#pragma unroll
    for (int it = 0; it < 6; ++it) {
        int s = tid + it * 256;
        int row = s / 24, sc = s - row * 24;
        int gc = (sc & 24) | ((sc ^ row) & 7);
        gl_lds16(Wnb + (size_t)n * 12288 + (size_t)row * 192 + gc * 8, Bs + (size_t)s * 8);
    }
#pragma unroll
    for (int it = 0; it < 3; ++it) {
        int s = tid + it * 256;
        int row = s / 24, sc = s - row * 24;
        int gc = (sc & 24) | ((sc ^ row) & 7);
        u16x8 v;
        if (gc < 8) {
            v = *(const u16x8*)(xn + (size_t)n * 2048 + row * 64 + (gc & 7) * 8);
        } else if (gc < 16) {
            v = *(const u16x8*)(xg1n + (size_t)n * 2048 + row * 64 + (gc & 7) * 8);
        } else {
            const u16* pp = p + (size_t)n * 2048 + row * 64 + (gc & 7) * 8;
            u16x8 q0 = *(const u16x8*)pp;
            u16x8 q1 = *(const u16x8*)(pp + PSTRIDE);
            u16x8 q2 = *(const u16x8*)(pp + 2 * PSTRIDE);
            u16x8 q3 = *(const u16x8*)(pp + 3 * PSTRIDE);
#pragma unroll
            for (int tt = 0; tt < 8; ++tt)
                v[tt] = f2bf(bf2f(q0[tt]) + bf2f(q1[tt]) + bf2f(q2[tt]) + bf2f(q3[tt]));
        }
        *(u16x8*)(As + (size_t)s * 8) = v;
    }
    float bv0 = bias[(size_t)n * 64 + wn2 + col];
    f32x4 acc[2];
#pragma unroll
    for (int mt = 0; mt < 2; ++mt)
#pragma unroll
        for (int r = 0; r < 4; ++r) acc[mt][r] = bv0;
    __syncthreads();

#pragma unroll
    for (int ks = 0; ks < 6; ++ks) {
        int c = c0l + ks * 4;
        int o = wn2 + ml;
        bf16x8 bfrag = *(const bf16x8*)(Bs + (o * 24 + ((c & 24) | ((c ^ (o & 7)) & 7))) * 8);
#pragma unroll
        for (int mt = 0; mt < 2; ++mt) {
            int m = mt * 16 + ml;
            bf16x8 afrag = *(const bf16x8*)(As + (m * 24 + ((c & 24) | ((c ^ (m & 7)) & 7))) * 8);
            acc[mt] = __builtin_amdgcn_mfma_f32_16x16x32_bf16(afrag, bfrag, acc[mt], 0, 0, 0);
        }
    }
#pragma unroll
    for (int mt = 0; mt < 2; ++mt)
#pragma unroll
        for (int r = 0; r < 4; ++r) {
            int b = mt * 16 + rl + r;
            out[((size_t)b * 2048 + n) * 64 + wn2 + col] = acc[mt][r];
        }
}

// ---------------------------------------------------------------- gconv_mfma (legacy fallback)
__global__ __launch_bounds__(256, 2)
void gconv_mfma(const float* __restrict__ x, const u16* __restrict__ xg1,
                const u16* __restrict__ p, const u16* __restrict__ Wpb,
                const float* __restrict__ bias, const float* __restrict__ E,
                float* __restrict__ out) {
    __shared__ alignas(16) float El[16 * 128];
    const int tid = threadIdx.x, lane = tid & 63, wave = tid >> 6;
    const int m0 = blockIdx.x * 128, nb = m0 & 2047, bB = m0 >> 11;
    const int wm = (wave >> 1) * 64, wn = (wave & 1) * 32;
    const int ml = lane & 15, c0l = lane >> 4;
    const int col_l = lane & 15, rl = (lane >> 4) * 4;

#pragma unroll
    for (int it = 0; it < 8; ++it) {
        int idx = tid + it * 256;
        El[idx] = E[(size_t)(nb + (idx & 127)) * 16 + (idx >> 7)];
    }
    __syncthreads();

    bf16x8 af[4][6];
#pragma unroll
    for (int i = 0; i < 4; ++i) {
        const int row = m0 + wm + i * 16 + ml;
        const int n = row & 2047;
#pragma unroll
        for (int ks = 0; ks < 2; ++ks) {
            const float* xp = x + (size_t)row * 64 + (c0l + ks * 4) * 8;
            float4 a = *(const float4*)xp, b4 = *(const float4*)(xp + 4);
            u16x8 v;
            v[0] = f2bf(a.x);  v[1] = f2bf(a.y);  v[2] = f2bf(a.z);  v[3] = f2bf(a.w);
            v[4] = f2bf(b4.x); v[5] = f2bf(b4.y); v[6] = f2bf(b4.z); v[7] = f2bf(b4.w);
            af[i][ks] = __builtin_bit_cast(bf16x8, v);
        }
#pragma unroll
        for (int ks = 2; ks < 4; ++ks)
            af[i][ks] = *(const bf16x8*)(xg1 + (size_t)row * 64 + (c0l + ks * 4 - 8) * 8);
#pragma unroll
        for (int ks = 4; ks < 6; ++ks) {
            const u16* pp = p + (size_t)n * 2048 + bB * 64 + (c0l + ks * 4 - 16) * 8;
            u16x8 q0 = *(const u16x8*)pp;
            u16x8 q1 = *(const u16x8*)(pp + PSTRIDE);
            u16x8 q2 = *(const u16x8*)(pp + 2 * PSTRIDE);
            u16x8 q3 = *(const u16x8*)(pp + 3 * PSTRIDE);
            u16x8 v;
#pragma unroll
            for (int tt = 0; tt < 8; ++tt)
                v[tt] = f2bf(bf2f(q0[tt]) + bf2f(q1[tt]) + bf2f(q2[tt]) + bf2f(q3[tt]));
            af[i][ks] = __builtin_bit_cast(bf16x8, v);
        }
    }

    f32x4 oacc[4][2];
#pragma unroll
    for (int i = 0; i < 4; ++i)
#pragma unroll
        for (int j = 0; j < 2; ++j)
#pragma unroll
            for (int r = 0; r < 4; ++r)
                oacc[i][j][r] = bias[(size_t)(nb + wm + i * 16 + rl + r) * 64 + wn + j * 16 + col_l];

#pragma unroll 2
    for (int d = 0; d < 16; ++d) {
        bf16x8 bv[2][6];
#pragma unroll
        for (int j = 0; j < 2; ++j) {
            const u16* wp = Wpb + (size_t)(d * 64 + wn + j * 16 + ml) * 192 + c0l * 8;
#pragma unroll
            for (int ks = 0; ks < 6; ++ks)
                bv[j][ks] = *(const bf16x8*)(wp + ks * 32);
        }
        f32x4 tmp[4][2] = {};
#pragma unroll
        for (int ks = 0; ks < 6; ++ks)
#pragma unroll
            for (int i = 0; i < 4; ++i)
#pragma unroll
                for (int j = 0; j < 2; ++j)
                    tmp[i][j] = __builtin_amdgcn_mfma_f32_16x16x32_bf16(af[i][ks], bv[j][ks], tmp[i][j], 0, 0, 0);
#pragma unroll
        for (int i = 0; i < 4; ++i) {
            f32x4 ev = *(const f32x4*)(El + d * 128 + wm + i * 16 + rl);
#pragma unroll
            for (int r = 0; r < 4; ++r)
#pragma unroll
                for (int j = 0; j < 2; ++j)
                    oacc[i][j][r] = fmaf(ev[r], tmp[i][j][r], oacc[i][j][r]);
        }
    }
#pragma unroll
    for (int i = 0; i < 4; ++i)
#pragma unroll
        for (int j = 0; j < 2; ++j)
#pragma unroll
            for (int r = 0; r < 4; ++r)
                out[(size_t)(m0 + wm + i * 16 + rl + r) * 64 + wn + j * 16 + col_l] = oacc[i][j][r];
}

// ---------------------------------------------------------------- launch
extern "C" void kernel_launch(void* const* d_in, const int* in_sizes, int n_in,
                              void* d_out, int out_size, void* d_ws, size_t ws_size,
                              hipStream_t stream) {
    const float* x   = (const float*)d_in[0];
    const float* E   = (const float*)d_in[1];
    const float* adj = (const float*)d_in[2];
    const float* Wp  = (const float*)d_in[3];
    const float* bp  = (const float*)d_in[4];
    const float* saw = (const float*)d_in[5];
    float* out = (float*)d_out;

    char* ws = (char*)d_ws;
    const size_t MB = 1u << 20;
    const int wn_mode = (ws_size >= 140 * MB) ? 1 : 0;

    u16*   Acat  = (u16*)(ws);                  // [0,16M)
    u16*   sawb  = (u16*)(ws + 16 * MB);        // [16,32M)
    u16*   XtT   = (u16*)(ws + 32 * MB);        // [32,40M)
    u16*   Wpb   = (u16*)(ws + 40 * MB);        // [40,40.4M) bf16
    float* bias  = (float*)(ws + 41 * MB);      // [41,41.5M)
    float* Wpbf  = (float*)(ws + 42 * MB);      // [42,42.8M) fp32
    u16*   part  = (u16*)(ws + 48 * MB);        // [48,80M)
    u16*   S_bf  = (u16*)(ws + 16 * MB);        // [16,24M)
    u16*   xg1T  = (u16*)(ws + 24 * MB);        // [24,32M)
    u16*   xg1o  = (u16*)(ws);                  // [0,8M)
    u16*   xn    = (u16*)(ws + 80 * MB);        // [80,88M)   wn only
    u16*   Wnb   = (u16*)(ws + 88 * MB);        // [88,138.4M) wn only

    preA<<<2896, 256, 0, stream>>>(E, adj, saw, x, Wp, bp, Acat, sawb, XtT,
                                   Wpb, Wpbf, bias, xn, wn_mode);

    gemm_bt256<<<dim3(8, 8, 4), 512, 0, stream>>>(Acat, sawb, part, 2048, 2048, 4096, 1024);
    rzmid<<<wn_mode ? 1792 : 1024, 256, 0, stream>>>(part, Acat, S_bf, E, Wpbf, Wnb);
    gemm_bt256<<<dim3(8, 8, 4), 512, 0, stream>>>(S_bf, XtT, part, 2048, 2048, 2048, 512);
    reduceT<<<dim3(32, 32), 256, 0, stream>>>(part, xg1o, xg1T, wn_mode);
    gemm_bt256<<<dim3(8, 8, 4), 512, 0, stream>>>(S_bf, xg1T, part, 2048, 2048, 2048, 512);

    if (wn_mode)
        gconv_wn<<<2048, 256, 0, stream>>>(xn, xg1o, part, Wnb, bias, out);
    else
        gconv_mfma<<<512, 256, 0, stream>>>(x, xg1o, part, Wpb, bias, E, out);
}

// Round 8
// 271.177 us; speedup vs baseline: 1.0574x; 1.0131x over previous
//
#include <hip/hip_runtime.h>

// AVWGCN: B=32, N=2048, C=64, O=64, K=3, D=16
// R21 changes vs R20 (fused preA 68us, occ 12.9%: zsm's VGPR=104/32KB-LDS appetite is
// welded to every streaming block; avg block lifetime ~6us; FETCH < fp32 inputs =>
// reads are L3-hits, phase is latency/concurrency-bound not HBM-bound):
//  - Split by RESOURCE PROFILE: preB = Wp+bias+conv+xT (lean: 12.5KB LDS, lb(256,4));
//    zsmW = zsm + wgen (fat: 32KB LDS). rzmid -> pure reduce_z. 8 dispatches.
//  - conv ILP 8 -> 16 float4 in flight per thread (768 blocks, exact coverage) to
//    attack the ~2TB/s per-thread-outstanding-load plateau.
// gemm_bt256 / reduceT / gconv unchanged.

typedef unsigned short u16;
typedef float f32x4 __attribute__((ext_vector_type(4)));
typedef __bf16 bf16x8 __attribute__((ext_vector_type(8)));
typedef unsigned short u16x8 __attribute__((ext_vector_type(8)));

#define PSTRIDE ((size_t)2048 * 2048)

__device__ __forceinline__ u16 f2bf(float f) {
    unsigned u = __float_as_uint(f);
    u += 0x7FFFu + ((u >> 16) & 1u);   // RNE
    return (u16)(u >> 16);
}
__device__ __forceinline__ float bf2f(u16 h) {
    return __uint_as_float((unsigned)h << 16);
}
__device__ __forceinline__ void gl_lds16(const void* g, void* l) {
    __builtin_amdgcn_global_load_lds(
        (const __attribute__((address_space(1))) unsigned*)g,
        (__attribute__((address_space(3))) unsigned*)l, 16, 0, 0);
}

// ---------------------------------------------------------------- preB (lean streaming)
// grid 1872: [0,16) Wp 4-pass | [16,80) bias | [80,848) conv 16x | [848,1872) x-T
__global__ __launch_bounds__(256, 4)
void preB(const float* __restrict__ E, const float* __restrict__ adj,
          const float* __restrict__ saw, const float* __restrict__ x,
          const float* __restrict__ Wp, const float* __restrict__ bp,
          u16* __restrict__ Acat, u16* __restrict__ sawb, u16* __restrict__ xtT,
          u16* __restrict__ Wpb, float* __restrict__ Wpbf,
          float* __restrict__ bias, u16* __restrict__ xn, int mode) {
    __shared__ __align__(16) char smem[12800];   // max(tw 12.3KB, t 8.3KB)
    const int bid = blockIdx.x, tid = threadIdx.x;

    if (bid < 16) {
        // ---- Wp Chebyshev combo, coalesced, 4-pass (48 ki per pass, tw[64][49])
        float (*tw)[49] = (float(*)[49])smem;
        const int d = bid;
        const float* base = Wp + (size_t)d * 12288;    // [k][i][o]
        const int o = tid & 63, seg = tid >> 6;        // seg 0..3
#pragma unroll
        for (int p = 0; p < 4; ++p) {
            if (p) __syncthreads();
#pragma unroll
            for (int j = 0; j < 12; ++j) {
                int kil = seg * 12 + j;                // 0..47
                int ki = p * 48 + kil;
                int k = ki >> 6, i = ki & 63;          // wave-uniform
                float v;
                if (k == 0)      v = base[i * 64 + o] - base[8192 + i * 64 + o];
                else if (k == 1) v = base[4096 + i * 64 + o];
                else             v = 2.f * base[8192 + i * 64 + o];
                tw[o][kil] = v;
            }
            __syncthreads();
#pragma unroll
            for (int it = 0; it < 3; ++it) {
                int idx = tid + it * 256;              // 0..767
                int oo = idx / 12, q = idx - oo * 12;  // q in [0,12)
                float v0 = tw[oo][q * 4], v1 = tw[oo][q * 4 + 1];
                float v2 = tw[oo][q * 4 + 2], v3 = tw[oo][q * 4 + 3];
                size_t dst = (size_t)(d * 64 + oo) * 192 + p * 48 + q * 4;
                *(float4*)(Wpbf + dst) = make_float4(v0, v1, v2, v3);
                *(ushort4*)(Wpb + dst) = make_ushort4(f2bf(v0), f2bf(v1), f2bf(v2), f2bf(v3));
            }
        }
    } else if (bid < 80) {
        // ---- bias = E @ bp
        const int nb = bid - 16;
#pragma unroll
        for (int it = 0; it < 8; ++it) {
            int idx = tid + it * 256;
            int n = nb * 32 + (idx >> 6), o = idx & 63;
            float s = 0.f;
#pragma unroll
            for (int d = 0; d < 16; ++d) s = fmaf(E[n * 16 + d], bp[d * 64 + o], s);
            bias[(size_t)n * 64 + o] = s;
        }
    } else if (bid < 848) {
        // ---- adj (1M float4) + saw (2M float4) -> bf16, 16 loads in flight
        const size_t NADJ = 1048576, STRIDE = (size_t)768 * 256;
        const size_t e0 = (size_t)(bid - 80) * 256 + tid;
        float4 v[16];
#pragma unroll
        for (int it = 0; it < 16; ++it) {
            size_t idx = e0 + (size_t)it * STRIDE;
            const float* src = (idx < NADJ) ? (adj + idx * 4) : (saw + (idx - NADJ) * 4);
            v[it] = *(const float4*)src;
        }
#pragma unroll
        for (int it = 0; it < 16; ++it) {
            size_t idx = e0 + (size_t)it * STRIDE;
            ushort4 o = make_ushort4(f2bf(v[it].x), f2bf(v[it].y), f2bf(v[it].z), f2bf(v[it].w));
            if (idx < NADJ) {
                size_t j = idx * 4;
                int n = (int)(j >> 11), c = (int)(j & 2047);
                *(ushort4*)(Acat + (size_t)n * 4096 + 2048 + c) = o;
            } else {
                *(ushort4*)(sawb + (idx - NADJ) * 4) = o;
            }
        }
    } else {
        // ---- x transpose (+xn in wn mode)
        u16 (*t)[65] = (u16(*)[65])smem;
        int local = bid - 848;
        int m0 = (local & 31) * 64, b = local >> 5;
        int c = tid & 63, g = tid >> 6;
#pragma unroll
        for (int r = 0; r < 16; ++r) {
            int mm = g * 16 + r;
            t[mm][c] = f2bf(x[((size_t)b * 2048 + m0 + mm) * 64 + c]);
        }
        __syncthreads();
#pragma unroll
        for (int r = 0; r < 16; ++r) {
            int cc = g * 16 + r;
            xtT[((size_t)b * 64 + cc) * 2048 + m0 + c] = t[c][cc];
        }
        if (mode) {
#pragma unroll
            for (int r = 0; r < 16; ++r) {
                int mm = g * 16 + r;
                xn[((size_t)(m0 + mm)) * 2048 + b * 64 + c] = t[mm][c];
            }
        }
    }
}

// ---------------------------------------------------------------- zsmW: zsm + wgen
// grid (wn): 1024 = [0,256) zsm | [256,1024) wgen.  non-wn: 256 (zsm only).
__global__ __launch_bounds__(256)
void zsmW(const float* __restrict__ E, const float* __restrict__ Wpbf,
          u16* __restrict__ Acat, u16* __restrict__ Wnb) {
    __shared__ __align__(16) char smem[32768];
    const int bid = blockIdx.x, tid = threadIdx.x;

    if (bid < 256) {
        // ---- zsm: softmax(relu(E@E^T)) rows [8b,8b+8) -> Acat bf16, 4-phase Et
        float* Et4 = (float*)smem;            // [4][2048] fp32 = 32KB
        const int r0 = bid * 8;
        float z[8][8] = {};
#pragma unroll
        for (int ph = 0; ph < 4; ++ph) {
            if (ph) __syncthreads();          // all reads of previous phase done
#pragma unroll
            for (int k = 0; k < 8; ++k) {
                const int n = tid + 256 * k;
                float4 e = ((const float4*)(E + (size_t)n * 16))[ph];
                Et4[0 * 2048 + n] = e.x; Et4[1 * 2048 + n] = e.y;
                Et4[2 * 2048 + n] = e.z; Et4[3 * 2048 + n] = e.w;
            }
            __syncthreads();
#pragma unroll
            for (int d = 0; d < 4; ++d) {     // global d = ph*4+d, ascending (bit-identical)
                const float* row = Et4 + d * 2048;
                float ev[8];
#pragma unroll
                for (int k = 0; k < 8; ++k) ev[k] = row[tid + 256 * k];
#pragma unroll
                for (int r = 0; r < 8; ++r) {
                    float e = row[r0 + r];    // broadcast
#pragma unroll
                    for (int k = 0; k < 8; ++k) z[r][k] = fmaf(e, ev[k], z[r][k]);
                }
            }
        }
        __syncthreads();                       // Et4 dead; reuse smem for reductions
        float (*redm)[8] = (float(*)[8])smem;
        float (*reds)[8] = (float(*)[8])(smem + 256);

        float mr[8];
#pragma unroll
        for (int r = 0; r < 8; ++r) {
            float m = 0.f;
#pragma unroll
            for (int k = 0; k < 8; ++k) { z[r][k] = fmaxf(z[r][k], 0.f); m = fmaxf(m, z[r][k]); }
            mr[r] = m;
        }
#pragma unroll
        for (int off = 32; off; off >>= 1)
#pragma unroll
            for (int r = 0; r < 8; ++r) mr[r] = fmaxf(mr[r], __shfl_xor(mr[r], off, 64));
        if ((tid & 63) == 0) {
#pragma unroll
            for (int r = 0; r < 8; ++r) redm[tid >> 6][r] = mr[r];
        }
        __syncthreads();
#pragma unroll
        for (int r = 0; r < 8; ++r)
            mr[r] = fmaxf(fmaxf(redm[0][r], redm[1][r]), fmaxf(redm[2][r], redm[3][r]));
        float sr[8];
#pragma unroll
        for (int r = 0; r < 8; ++r) {
            float s = 0.f;
#pragma unroll
            for (int k = 0; k < 8; ++k) { z[r][k] = __expf(z[r][k] - mr[r]); s += z[r][k]; }
            sr[r] = s;
        }
#pragma unroll
        for (int off = 32; off; off >>= 1)
#pragma unroll
            for (int r = 0; r < 8; ++r) sr[r] += __shfl_xor(sr[r], off, 64);
        if ((tid & 63) == 0) {
#pragma unroll
            for (int r = 0; r < 8; ++r) reds[tid >> 6][r] = sr[r];
        }
        __syncthreads();
#pragma unroll
        for (int r = 0; r < 8; ++r) {
            float inv = 1.f / (reds[0][r] + reds[1][r] + reds[2][r] + reds[3][r]);
            u16* orow = Acat + (size_t)(r0 + r) * 4096;
#pragma unroll
            for (int k = 0; k < 8; ++k) orow[tid + 256 * k] = f2bf(z[r][k] * inv);
        }
    } else {
        // ---- wgen: Wn = E @ Wpbf (wn mode only)
        float* Es = (float*)smem;
        const int w = bid - 256;
        const int c0 = (w % 12) * 1024, n0 = (w / 12) * 32;
        for (int j = tid; j < 512; j += 256) Es[j] = E[(size_t)n0 * 16 + j];
        float4 wf[16];
#pragma unroll
        for (int d = 0; d < 16; ++d)
            wf[d] = *(const float4*)(Wpbf + (size_t)d * 12288 + c0 + tid * 4);
        __syncthreads();
        for (int nl = 0; nl < 32; ++nl) {
            float4 s = make_float4(0.f, 0.f, 0.f, 0.f);
#pragma unroll
            for (int d = 0; d < 16; ++d) {
                float e = Es[nl * 16 + d];
                s.x = fmaf(e, wf[d].x, s.x);
                s.y = fmaf(e, wf[d].y, s.y);
                s.z = fmaf(e, wf[d].z, s.z);
                s.w = fmaf(e, wf[d].w, s.w);
            }
            *(ushort4*)(Wnb + (size_t)(n0 + nl) * 12288 + c0 + tid * 4) =
                make_ushort4(f2bf(s.x), f2bf(s.y), f2bf(s.z), f2bf(s.w));
        }
    }
}

// ---------------------------------------------------------------- reduce_z
// grid-stride: 1024 blocks x 4 iterations
__global__ __launch_bounds__(256)
void reduce_z(const u16* __restrict__ p, const u16* __restrict__ Acat,
              u16* __restrict__ S) {
    const size_t base = ((size_t)blockIdx.x * 256 + threadIdx.x) * 4;
    const size_t STRIDE = (size_t)1024 * 256 * 4;
#pragma unroll
    for (int it = 0; it < 4; ++it) {
        size_t j = base + (size_t)it * STRIDE;
        ushort4 p0 = *(const ushort4*)(p + j);
        ushort4 p1 = *(const ushort4*)(p + PSTRIDE + j);
        ushort4 p2 = *(const ushort4*)(p + 2 * PSTRIDE + j);
        ushort4 p3 = *(const ushort4*)(p + 3 * PSTRIDE + j);
        int row = (int)(j >> 11), col = (int)(j & 2047);
        ushort4 sp = *(const ushort4*)(Acat + (size_t)row * 4096 + col);
        ushort4 ad = *(const ushort4*)(Acat + (size_t)row * 4096 + 2048 + col);
        float z0 = bf2f(p0.x) + bf2f(p1.x) + bf2f(p2.x) + bf2f(p3.x);
        float z1 = bf2f(p0.y) + bf2f(p1.y) + bf2f(p2.y) + bf2f(p3.y);
        float z2 = bf2f(p0.z) + bf2f(p1.z) + bf2f(p2.z) + bf2f(p3.z);
        float z3 = bf2f(p0.w) + bf2f(p1.w) + bf2f(p2.w) + bf2f(p3.w);
        float s0 = 1.f / (1.f + __expf(-z0)), s1 = 1.f / (1.f + __expf(-z1));
        float s2 = 1.f / (1.f + __expf(-z2)), s3 = 1.f / (1.f + __expf(-z3));
        ushort4 o = make_ushort4(
            f2bf(s0 * bf2f(ad.x) + (1.f - s0) * bf2f(sp.x)),
            f2bf(s1 * bf2f(ad.y) + (1.f - s1) * bf2f(sp.y)),
            f2bf(s2 * bf2f(ad.z) + (1.f - s2) * bf2f(sp.z)),
            f2bf(s3 * bf2f(ad.w) + (1.f - s3) * bf2f(sp.w)));
        *(ushort4*)(S + j) = o;
    }
}

// ---------------------------------------------------------------- GEMM 256x256, BK=64, split-K
__global__ __launch_bounds__(512, 2)
void gemm_bt256(const u16* __restrict__ A, const u16* __restrict__ Bt,
                u16* __restrict__ Cp, int M, int N, int K, int Kh) {
    __shared__ alignas(16) u16 As[2][256 * 64];
    __shared__ alignas(16) u16 Bs[2][256 * 64];
    const int tid = threadIdx.x, lane = tid & 63, wave = tid >> 6;

    const int nbx = gridDim.x, nby = gridDim.y, nbz = gridDim.z;
    const int nwg = nbx * nby * nbz;
    int lin = (blockIdx.z * nby + blockIdx.y) * nbx + blockIdx.x;
    if ((nwg & 7) == 0) lin = (lin & 7) * (nwg >> 3) + (lin >> 3);
    const int bz = lin / (nbx * nby);
    const int r2 = lin - bz * nbx * nby;
    const int by = r2 / nbx, bx = r2 - by * nbx;

    const int m0 = by * 256, n0 = bx * 256;
    const int kbeg = bz * Kh;
    const int NT = Kh >> 6;
    const int wm = (wave >> 2) * 128, wn = (wave & 3) * 64;
    const int ml = lane & 15, c0l = lane >> 4;

    int sI[4], rowI[4], gcI[4];
#pragma unroll
    for (int r = 0; r < 4; ++r) {
        int s = r * 512 + tid;
        sI[r] = s; rowI[r] = s >> 3; gcI[r] = (s & 7) ^ ((s >> 3) & 7);
    }

    f32x4 acc[8][4] = {};
    bf16x8 af[4][2], bv[2][2];

#define LOADA(r_, kt_, buf_) \
    gl_lds16(A + (size_t)(m0 + rowI[r_]) * K + (kt_) + gcI[r_] * 8, \
             &As[buf_][sI[r_] * 8])
#define LOADB(r_, kt_, buf_) \
    gl_lds16(Bt + (size_t)(n0 + rowI[r_]) * K + (kt_) + gcI[r_] * 8, \
             &Bs[buf_][sI[r_] * 8])

#define DSRA(qa_) \
    _Pragma("unroll") \
    for (int i = 0; i < 4; ++i) { \
        const int mr = wm + (qa_) * 64 + i * 16 + ml; \
        _Pragma("unroll") \
        for (int ks = 0; ks < 2; ++ks) \
            af[i][ks] = *(const bf16x8*)(Asc + mr * 64 + (((c0l + ks * 4) ^ (mr & 7)) * 8)); \
    }
#define DSRB(qb_) \
    _Pragma("unroll") \
    for (int j = 0; j < 2; ++j) { \
        const int nr = wn + (qb_) * 32 + j * 16 + ml; \
        _Pragma("unroll") \
        for (int ks = 0; ks < 2; ++ks) \
            bv[j][ks] = *(const bf16x8*)(Bsc + nr * 64 + (((c0l + ks * 4) ^ (nr & 7)) * 8)); \
    }
#define MMQ(io_, jo_) \
    __builtin_amdgcn_s_barrier(); \
    asm volatile("s_waitcnt lgkmcnt(0)" ::: "memory"); \
    __builtin_amdgcn_s_setprio(1); \
    _Pragma("unroll") \
    for (int ks = 0; ks < 2; ++ks) \
        _Pragma("unroll") \
        for (int i = 0; i < 4; ++i) \
            _Pragma("unroll") \
            for (int j = 0; j < 2; ++j) \
                acc[(io_) + i][(jo_) + j] = __builtin_amdgcn_mfma_f32_16x16x32_bf16( \
                    af[i][ks], bv[j][ks], acc[(io_) + i][(jo_) + j], 0, 0, 0); \
    __builtin_amdgcn_s_setprio(0);

#pragma unroll
    for (int r = 0; r < 4; ++r) LOADA(r, kbeg, 0);
#pragma unroll
    for (int r = 0; r < 4; ++r) LOADB(r, kbeg, 0);
    asm volatile("s_waitcnt vmcnt(0)" ::: "memory");
    __builtin_amdgcn_s_barrier();

    for (int t = 0; t < NT - 1; ++t) {
        const int cur = t & 1, nxt = cur ^ 1;
        const u16* Asc = As[cur];
        const u16* Bsc = Bs[cur];
        const int k1 = kbeg + (t + 1) * 64;

        DSRA(0); DSRB(0);
        LOADB(0, k1, nxt); LOADB(1, k1, nxt);
        MMQ(0, 0);
        __builtin_amdgcn_s_barrier();

        DSRB(1);
        LOADB(2, k1, nxt); LOADB(3, k1, nxt);
        MMQ(0, 2);
        asm volatile("s_waitcnt vmcnt(4)" ::: "memory");
        __builtin_amdgcn_s_barrier();

        DSRA(1);
        LOADA(0, k1, nxt); LOADA(2, k1, nxt);
        MMQ(4, 2);
        __builtin_amdgcn_s_barrier();

        DSRB(0);
        LOADA(1, k1, nxt); LOADA(3, k1, nxt);
        MMQ(4, 0);
        asm volatile("s_waitcnt vmcnt(2)" ::: "memory");
        __builtin_amdgcn_s_barrier();
    }

    {
        const int cur = (NT - 1) & 1;
        const u16* Asc = As[cur];
        const u16* Bsc = Bs[cur];

        DSRA(0); DSRB(0);
        MMQ(0, 0);
        __builtin_amdgcn_s_barrier();

        DSRB(1);
        MMQ(0, 2);
        asm volatile("s_waitcnt vmcnt(0)" ::: "memory");
        __builtin_amdgcn_s_barrier();

        DSRA(1);
        MMQ(4, 2);
        __builtin_amdgcn_s_barrier();

        DSRB(0);
        MMQ(4, 0);
    }

#undef LOADA
#undef LOADB
#undef DSRA
#undef DSRB
#undef MMQ

    const int col_l = lane & 15, rl = (lane >> 4) * 4;
    u16* Cz = Cp + (size_t)bz * M * N;
#pragma unroll
    for (int i = 0; i < 8; ++i)
#pragma unroll
        for (int j = 0; j < 4; ++j)
#pragma unroll
            for (int r = 0; r < 4; ++r) {
                int row = m0 + wm + i * 16 + rl + r;
                int col = n0 + wn + j * 16 + col_l;
                Cz[(size_t)row * N + col] = f2bf(acc[i][j][r]);
            }
}

// ---------------------------------------------------------------- reduceT
__global__ __launch_bounds__(256)
void reduceT(const u16* __restrict__ p, u16* __restrict__ xg1o,
             u16* __restrict__ xg1T, int mode) {
    __shared__ u16 t[64][68];
    int bx = blockIdx.x * 64, by = blockIdx.y * 64;
    int cg = threadIdx.x & 15, rg = threadIdx.x >> 4;
    int b = bx >> 6;
#pragma unroll
    for (int rr = 0; rr < 4; ++rr) {
        int row = rg * 4 + rr;
        size_t idx = (size_t)(by + row) * 2048 + bx + cg * 4;
        ushort4 q0 = *(const ushort4*)(p + idx);
        ushort4 q1 = *(const ushort4*)(p + PSTRIDE + idx);
        ushort4 q2 = *(const ushort4*)(p + 2 * PSTRIDE + idx);
        ushort4 q3 = *(const ushort4*)(p + 3 * PSTRIDE + idx);
        ushort4 v = make_ushort4(
            f2bf(bf2f(q0.x) + bf2f(q1.x) + bf2f(q2.x) + bf2f(q3.x)),
            f2bf(bf2f(q0.y) + bf2f(q1.y) + bf2f(q2.y) + bf2f(q3.y)),
            f2bf(bf2f(q0.z) + bf2f(q1.z) + bf2f(q2.z) + bf2f(q3.z)),
            f2bf(bf2f(q0.w) + bf2f(q1.w) + bf2f(q2.w) + bf2f(q3.w)));
        if (mode) *(ushort4*)(xg1o + idx) = v;
        else      *(ushort4*)(xg1o + ((size_t)b * 2048 + by + row) * 64 + cg * 4) = v;
        *(ushort4*)(&t[row][cg * 4]) = v;
    }
    __syncthreads();
    int c = threadIdx.x & 63, g = threadIdx.x >> 6;
#pragma unroll
    for (int r = 0; r < 16; ++r) {
        int row = g * 16 + r;
        xg1T[(size_t)(bx + row) * 2048 + by + c] = t[c][row];
    }
}

// ---------------------------------------------------------------- gconv_wn (Wn mode)
__global__ __launch_bounds__(256, 4)
void gconv_wn(const u16* __restrict__ xn, const u16* __restrict__ xg1n,
              const u16* __restrict__ p, const u16* __restrict__ Wnb,
              const float* __restrict__ bias, float* __restrict__ out) {
    __shared__ alignas(16) u16 As[32 * 192];
    __shared__ alignas(16) u16 Bs[64 * 192];
    const int n = blockIdx.x, tid = threadIdx.x;
    const int lane = tid & 63, wave = tid >> 6;
    const int wn2 = wave * 16;
    const int ml = lane & 15, c0l = lane >> 4;
    const int col = lane & 15, rl = (lane >> 4) * 4;

#pragma unroll
    for (int it = 0; it < 6; ++it) {
        int s = tid + it * 256;
        int row = s / 24, sc = s - row * 24;
        int gc = (sc & 24) | ((sc ^ row) & 7);
        gl_lds16(Wnb + (size_t)n * 12288 + (size_t)row * 192 + gc * 8, Bs + (size_t)s * 8);
    }
#pragma unroll
    for (int it = 0; it < 3; ++it) {
        int s = tid + it * 256;
        int row = s / 24, sc = s - row * 24;
        int gc = (sc & 24) | ((sc ^ row) & 7);
        u16x8 v;
        if (gc < 8) {
            v = *(const u16x8*)(xn + (size_t)n * 2048 + row * 64 + (gc & 7) * 8);
        } else if (gc < 16) {
            v = *(const u16x8*)(xg1n + (size_t)n * 2048 + row * 64 + (gc & 7) * 8);
        } else {
            const u16* pp = p + (size_t)n * 2048 + row * 64 + (gc & 7) * 8;
            u16x8 q0 = *(const u16x8*)pp;
            u16x8 q1 = *(const u16x8*)(pp + PSTRIDE);
            u16x8 q2 = *(const u16x8*)(pp + 2 * PSTRIDE);
            u16x8 q3 = *(const u16x8*)(pp + 3 * PSTRIDE);
#pragma unroll
            for (int tt = 0; tt < 8; ++tt)
                v[tt] = f2bf(bf2f(q0[tt]) + bf2f(q1[tt]) + bf2f(q2[tt]) + bf2f(q3[tt]));
        }
        *(u16x8*)(As + (size_t)s * 8) = v;
    }
    float bv0 = bias[(size_t)n * 64 + wn2 + col];
    f32x4 acc[2];
#pragma unroll
    for (int mt = 0; mt < 2; ++mt)
#pragma unroll
        for (int r = 0; r < 4; ++r) acc[mt][r] = bv0;
    __syncthreads();

#pragma unroll
    for (int ks = 0; ks < 6; ++ks) {
        int c = c0l + ks * 4;
        int o = wn2 + ml;
        bf16x8 bfrag = *(const bf16x8*)(Bs + (o * 24 + ((c & 24) | ((c ^ (o & 7)) & 7))) * 8);
#pragma unroll
        for (int mt = 0; mt < 2; ++mt) {
            int m = mt * 16 + ml;
            bf16x8 afrag = *(const bf16x8*)(As + (m * 24 + ((c & 24) | ((c ^ (m & 7)) & 7))) * 8);
            acc[mt] = __builtin_amdgcn_mfma_f32_16x16x32_bf16(afrag, bfrag, acc[mt], 0, 0, 0);
        }
    }
#pragma unroll
    for (int mt = 0; mt < 2; ++mt)
#pragma unroll
        for (int r = 0; r < 4; ++r) {
            int b = mt * 16 + rl + r;
            out[((size_t)b * 2048 + n) * 64 + wn2 + col] = acc[mt][r];
        }
}

// ---------------------------------------------------------------- gconv_mfma (legacy fallback)
__global__ __launch_bounds__(256, 2)
void gconv_mfma(const float* __restrict__ x, const u16* __restrict__ xg1,
                const u16* __restrict__ p, const u16* __restrict__ Wpb,
                const float* __restrict__ bias, const float* __restrict__ E,
                float* __restrict__ out) {
    __shared__ alignas(16) float El[16 * 128];
    const int tid = threadIdx.x, lane = tid & 63, wave = tid >> 6;
    const int m0 = blockIdx.x * 128, nb = m0 & 2047, bB = m0 >> 11;
    const int wm = (wave >> 1) * 64, wn = (wave & 1) * 32;
    const int ml = lane & 15, c0l = lane >> 4;
    const int col_l = lane & 15, rl = (lane >> 4) * 4;

#pragma unroll
    for (int it = 0; it < 8; ++it) {
        int idx = tid + it * 256;
        El[idx] = E[(size_t)(nb + (idx & 127)) * 16 + (idx >> 7)];
    }
    __syncthreads();

    bf16x8 af[4][6];
#pragma unroll
    for (int i = 0; i < 4; ++i) {
        const int row = m0 + wm + i * 16 + ml;
        const int n = row & 2047;
#pragma unroll
        for (int ks = 0; ks < 2; ++ks) {
            const float* xp = x + (size_t)row * 64 + (c0l + ks * 4) * 8;
            float4 a = *(const float4*)xp, b4 = *(const float4*)(xp + 4);
            u16x8 v;
            v[0] = f2bf(a.x);  v[1] = f2bf(a.y);  v[2] = f2bf(a.z);  v[3] = f2bf(a.w);
            v[4] = f2bf(b4.x); v[5] = f2bf(b4.y); v[6] = f2bf(b4.z); v[7] = f2bf(b4.w);
            af[i][ks] = __builtin_bit_cast(bf16x8, v);
        }
#pragma unroll
        for (int ks = 2; ks < 4; ++ks)
            af[i][ks] = *(const bf16x8*)(xg1 + (size_t)row * 64 + (c0l + ks * 4 - 8) * 8);
#pragma unroll
        for (int ks = 4; ks < 6; ++ks) {
            const u16* pp = p + (size_t)n * 2048 + bB * 64 + (c0l + ks * 4 - 16) * 8;
            u16x8 q0 = *(const u16x8*)pp;
            u16x8 q1 = *(const u16x8*)(pp + PSTRIDE);
            u16x8 q2 = *(const u16x8*)(pp + 2 * PSTRIDE);
            u16x8 q3 = *(const u16x8*)(pp + 3 * PSTRIDE);
            u16x8 v;
#pragma unroll
            for (int tt = 0; tt < 8; ++tt)
                v[tt] = f2bf(bf2f(q0[tt]) + bf2f(q1[tt]) + bf2f(q2[tt]) + bf2f(q3[tt]));
            af[i][ks] = __builtin_bit_cast(bf16x8, v);
        }
    }

    f32x4 oacc[4][2];
#pragma unroll
    for (int i = 0; i < 4; ++i)
#pragma unroll
        for (int j = 0; j < 2; ++j)
#pragma unroll
            for (int r = 0; r < 4; ++r)
                oacc[i][j][r] = bias[(size_t)(nb + wm + i * 16 + rl + r) * 64 + wn + j * 16 + col_l];

#pragma unroll 2
    for (int d = 0; d < 16; ++d) {
        bf16x8 bv[2][6];
#pragma unroll
        for (int j = 0; j < 2; ++j) {
            const u16* wp = Wpb + (size_t)(d * 64 + wn + j * 16 + ml) * 192 + c0l * 8;
#pragma unroll
            for (int ks = 0; ks < 6; ++ks)
                bv[j][ks] = *(const bf16x8*)(wp + ks * 32);
        }
        f32x4 tmp[4][2] = {};
#pragma unroll
        for (int ks = 0; ks < 6; ++ks)
#pragma unroll
            for (int i = 0; i < 4; ++i)
#pragma unroll
                for (int j = 0; j < 2; ++j)
                    tmp[i][j] = __builtin_amdgcn_mfma_f32_16x16x32_bf16(af[i][ks], bv[j][ks], tmp[i][j], 0, 0, 0);
#pragma unroll
        for (int i = 0; i < 4; ++i) {
            f32x4 ev = *(const f32x4*)(El + d * 128 + wm + i * 16 + rl);
#pragma unroll
            for (int r = 0; r < 4; ++r)
#pragma unroll
                for (int j = 0; j < 2; ++j)
                    oacc[i][j][r] = fmaf(ev[r], tmp[i][j][r], oacc[i][j][r]);
        }
    }
#pragma unroll
    for (int i = 0; i < 4; ++i)
#pragma unroll
        for (int j = 0; j < 2; ++j)
#pragma unroll
            for (int r = 0; r < 4; ++r)
                out[(size_t)(m0 + wm + i * 16 + rl + r) * 64 + wn + j * 16 + col_l] = oacc[i][j][r];
}

// ---------------------------------------------------------------- launch
extern "C" void kernel_launch(void* const* d_in, const int* in_sizes, int n_in,
                              void* d_out, int out_size, void* d_ws, size_t ws_size,
                              hipStream_t stream) {
    const float* x   = (const float*)d_in[0];
    const float* E   = (const float*)d_in[1];
    const float* adj = (const float*)d_in[2];
    const float* Wp  = (const float*)d_in[3];
    const float* bp  = (const float*)d_in[4];
    const float* saw = (const float*)d_in[5];
    float* out = (float*)d_out;

    char* ws = (char*)d_ws;
    const size_t MB = 1u << 20;
    const int wn_mode = (ws_size >= 140 * MB) ? 1 : 0;

    u16*   Acat  = (u16*)(ws);                  // [0,16M)
    u16*   sawb  = (u16*)(ws + 16 * MB);        // [16,32M)
    u16*   XtT   = (u16*)(ws + 32 * MB);        // [32,40M)
    u16*   Wpb   = (u16*)(ws + 40 * MB);        // [40,40.4M) bf16
    float* bias  = (float*)(ws + 41 * MB);      // [41,41.5M)
    float* Wpbf  = (float*)(ws + 42 * MB);      // [42,42.8M) fp32
    u16*   part  = (u16*)(ws + 48 * MB);        // [48,80M)
    u16*   S_bf  = (u16*)(ws + 16 * MB);        // [16,24M)
    u16*   xg1T  = (u16*)(ws + 24 * MB);        // [24,32M)
    u16*   xg1o  = (u16*)(ws);                  // [0,8M)
    u16*   xn    = (u16*)(ws + 80 * MB);        // [80,88M)   wn only
    u16*   Wnb   = (u16*)(ws + 88 * MB);        // [88,138.4M) wn only

    preB<<<1872, 256, 0, stream>>>(E, adj, saw, x, Wp, bp, Acat, sawb, XtT,
                                   Wpb, Wpbf, bias, xn, wn_mode);
    zsmW<<<wn_mode ? 1024 : 256, 256, 0, stream>>>(E, Wpbf, Acat, Wnb);

    gemm_bt256<<<dim3(8, 8, 4), 512, 0, stream>>>(Acat, sawb, part, 2048, 2048, 4096, 1024);
    reduce_z<<<1024, 256, 0, stream>>>(part, Acat, S_bf);
    gemm_bt256<<<dim3(8, 8, 4), 512, 0, stream>>>(S_bf, XtT, part, 2048, 2048, 2048, 512);
    reduceT<<<dim3(32, 32), 256, 0, stream>>>(part, xg1o, xg1T, wn_mode);
    gemm_bt256<<<dim3(8, 8, 4), 512, 0, stream>>>(S_bf, xg1T, part, 2048, 2048, 2048, 512);

    if (wn_mode)
        gconv_wn<<<2048, 256, 0, stream>>>(xn, xg1o, part, Wnb, bias, out);
    else
        gconv_mfma<<<512, 256, 0, stream>>>(x, xg1o, part, Wpb, bias, E, out);
}